// Round 8
// baseline (392.473 us; speedup 1.0000x reference)
//
#include <hip/hip_runtime.h>
#include <math.h>

#define PDIM 8
#define BSZ 256
#define CEEG 22
#define TLEN 1000
#define KW 12
#define C2 96
#define TOUT 989
#define TSTR 992          // padded h2 row stride (16B-aligned float4 stores)
#define NSWEEP 5          // 4 FAILS (absmax 3.6e-2); 5 = machine floor. LOCKED.
#define NT8 8             // k3 t-tiles of 128
#define NPART (BSZ*NT8*2) // BN2 stat partial groups (2 n-groups per tile)

typedef __attribute__((ext_vector_type(8))) short short8;
typedef __attribute__((ext_vector_type(4))) float floatx4;

// ---- workspace layout (in floats) ----
#define OFF_H1   ((size_t)0)
#define SZ_H1    ((size_t)BSZ*CEEG*TLEN)
#define OFF_H2   (OFF_H1 + SZ_H1)
#define SZ_H2    ((size_t)BSZ*C2*TSTR)
#define OFF_S    (OFF_H2 + SZ_H2)
#define SZ_S     ((size_t)BSZ*3*1024)
// Whi/Wlo (bf16, 96x288 each) ALIAS the S region: written by k0w, consumed by
// k3, then S is (re)written later by k5. No lifetime overlap.
#define OFF_WH   (OFF_S)
#define OFF_WL   (OFF_S + (size_t)13824)
#define OFF_QQT  (OFF_S + SZ_S)
#define SZ_QQT   ((size_t)BSZ*3*256)
#define OFF_KKT  (OFF_QQT + SZ_QQT)
#define OFF_VP   (OFF_KKT + SZ_QQT)
#define SZ_VP    ((size_t)BSZ*256)
#define OFF_P1   (OFF_VP + SZ_VP)
#define SZ_P1    ((size_t)BSZ*44)
#define OFF_P2   (OFF_P1 + SZ_P1)
#define SZ_P2    ((size_t)NPART*192)
#define OFF_BN1  (OFF_P2 + SZ_P2)
#define OFF_BN2  (OFF_BN1 + (size_t)64)

__device__ __forceinline__ float elu_f(float z) { return z > 0.f ? z : expm1f(z); }

__device__ __forceinline__ unsigned short f2bf(float x) {
    unsigned u = __float_as_uint(x);
    u += 0x7fffu + ((u >> 16) & 1u);
    return (unsigned short)(u >> 16);
}
__device__ __forceinline__ float bf2f(unsigned short h) {
    return __uint_as_float(((unsigned)h) << 16);
}

// ================= K0w: precompute split-bf16 weights Whi/Wlo [96][288] ==========
__global__ __launch_bounds__(256) void k0_wsplit(const float* __restrict__ w2,
        unsigned short* __restrict__ Whi, unsigned short* __restrict__ Wlo) {
    int i = blockIdx.x*256 + threadIdx.x;
    if (i >= 96*288) return;
    int o = i / 288, kap = i - o*288;
    float v = (kap < 264) ? w2[o*264 + kap] : 0.f;
    unsigned short h = f2bf(v);
    float lo = v - bf2f(h);
    Whi[i] = h;
    Wlo[i] = f2bf(lo);
}

// ================= K1: conv1 (22ch spatial filter) + BN1 partial stats ==========
__global__ __launch_bounds__(256) void k1_conv1(const float* __restrict__ x,
        const float* __restrict__ w1, float* __restrict__ h1,
        float* __restrict__ part1) {
    __shared__ float sw[CEEG*CEEG];       // [o][c]
    __shared__ float red[4][44];
    int b = blockIdx.x;
    int tid = threadIdx.x;
    for (int i = tid; i < CEEG*CEEG; i += 256) sw[i] = w1[i];
    __syncthreads();
    float sum[CEEG], sumsq[CEEG];
    #pragma unroll
    for (int o = 0; o < CEEG; ++o) { sum[o] = 0.f; sumsq[o] = 0.f; }
    const float* xb = x + (size_t)b*CEEG*TLEN;
    float* hb = h1 + (size_t)b*CEEG*TLEN;
    for (int it = 0; it < 4; ++it) {
        int t = it*256 + tid;
        if (t < TLEN) {
            float acc[CEEG];
            #pragma unroll
            for (int o = 0; o < CEEG; ++o) acc[o] = 0.f;
            #pragma unroll 2
            for (int c = 0; c < CEEG; ++c) {
                float xv = xb[c*TLEN + t];
                #pragma unroll
                for (int o = 0; o < CEEG; ++o) acc[o] = fmaf(xv, sw[o*CEEG + c], acc[o]);
            }
            #pragma unroll
            for (int o = 0; o < CEEG; ++o) {
                hb[o*TLEN + t] = acc[o];
                sum[o]  += acc[o];
                sumsq[o] += acc[o]*acc[o];
            }
        }
    }
    int lane = tid & 63, wv = tid >> 6;
    #pragma unroll
    for (int o = 0; o < CEEG; ++o) {
        float s = sum[o], s2 = sumsq[o];
        for (int off = 32; off > 0; off >>= 1) {
            s  += __shfl_down(s,  off, 64);
            s2 += __shfl_down(s2, off, 64);
        }
        if (lane == 0) { red[wv][o] = s; red[wv][CEEG + o] = s2; }
    }
    __syncthreads();
    if (tid < 44) {
        part1[(size_t)b*44 + tid] = red[0][tid] + red[1][tid] + red[2][tid] + red[3][tid];
    }
}

// ================= K2: finalize BN1 params (1 block / channel) ==========
__global__ __launch_bounds__(64) void k2_bn1(const float* __restrict__ part1,
        const float* __restrict__ g, const float* __restrict__ bta, float* __restrict__ p1) {
    int c = blockIdx.x, t = threadIdx.x;
    float s = 0.f, s2 = 0.f;
    for (int blk = t; blk < BSZ; blk += 64) {
        s  += part1[(size_t)blk*44 + c];
        s2 += part1[(size_t)blk*44 + CEEG + c];
    }
    for (int off = 32; off > 0; off >>= 1) {
        s  += __shfl_down(s,  off, 64);
        s2 += __shfl_down(s2, off, 64);
    }
    if (t == 0) {
        double N = (double)BSZ * (double)TLEN;
        double mu = (double)s / N, var = (double)s2 / N - mu*mu;
        double scale = (double)g[c] / sqrt(var + 1e-5);
        p1[c] = (float)scale;
        p1[CEEG + c] = (float)((double)bta[c] - mu*scale);
    }
}

// ===== K3 v8: split-bf16 MFMA GEMM, 256 thr, packed-E (hi|lo u32) Xt build ====
// C[96][128] = W[96][288] x X[288][128]. Waves: mg = w&1 (o half), ng = w>>1
// (t half). A-frags: global->register direct, double-buffered. E packed as
// u32 (hi16<<16)|(lo16 trunc) once; Xt build is pure bit-ops.
__global__ __launch_bounds__(256) void k3_conv2(const float* __restrict__ h1,
        const unsigned short* __restrict__ WhiG, const unsigned short* __restrict__ WloG,
        const float* __restrict__ p1, float* __restrict__ h2, float* __restrict__ part2) {
    __shared__ unsigned Epack[22*152];      // (hi16<<16)|(lo16), [c][tt<139]
    __shared__ unsigned short ctab[288];    // kappa -> E offset (c*152+k), 0xFFFF = pad
    __shared__ short XhiL[128*40];          // Xt chunk [t][40], 32 used
    __shared__ short XloL[128*40];
    int b = blockIdx.x;
    int tile = blockIdx.y;                  // 0..7
    int t0 = tile * 128;
    int tid = threadIdx.x;
    int lane = tid & 63, w = tid >> 6;
    int r16 = lane & 15, q = lane >> 4;
    int mg = w & 1, ng = w >> 1;
    const float* hb = h1 + (size_t)b*CEEG*TLEN;

    // stage E window [t0, t0+138] with BN1+ELU, packed hi|lo; zero beyond TLEN
    for (int i = tid; i < 22*139; i += 256) {
        int c = i / 139, tt = i - c*139;
        int t = t0 + tt;
        unsigned pk = 0u;
        if (t < TLEN) {
            float v = elu_f(fmaf(hb[c*TLEN + t], p1[c], p1[CEEG + c]));
            unsigned uv = __float_as_uint(v);
            unsigned hi = uv & 0xFFFF0000u;
            float lo = v - __uint_as_float(hi);
            pk = hi | (__float_as_uint(lo) >> 16);
        }
        Epack[c*152 + tt] = pk;
    }
    for (int i = tid; i < 288; i += 256) {
        int c = i / 12, k = i - c*12;
        ctab[i] = (i < 264) ? (unsigned short)(c*152 + k) : (unsigned short)0xFFFF;
    }

    // A-frag row pointers (this lane's 16B segment per m-tile)
    const unsigned short* ahP[3];
    const unsigned short* alP[3];
    #pragma unroll
    for (int m = 0; m < 3; ++m) {
        int row = mg*48 + m*16 + r16;
        ahP[m] = WhiG + row*288 + q*8;
        alP[m] = WloG + row*288 + q*8;
    }
    short8 ahC[3], alC[3];
    #pragma unroll
    for (int m = 0; m < 3; ++m) {
        ahC[m] = *(const short8*)&ahP[m][0];
        alC[m] = *(const short8*)&alP[m][0];
    }

    floatx4 acc[3][4];
    #pragma unroll
    for (int m = 0; m < 3; ++m)
        #pragma unroll
        for (int nf = 0; nf < 4; ++nf) acc[m][nf] = (floatx4){0.f, 0.f, 0.f, 0.f};

    __syncthreads();                        // Epack ready

    // build Xt for chunk 0 (tasks: u -> row u>>2, 16B chunk u&3)
    #pragma unroll
    for (int s = 0; s < 2; ++s) {
        int u = tid + s*256;
        int t = u >> 2, c4 = u & 3;
        const unsigned short* ct = &ctab[c4*8];
        unsigned dh[4], dl[4];
        #pragma unroll
        for (int jp = 0; jp < 4; ++jp) {
            unsigned short o0 = ct[2*jp], o1 = ct[2*jp+1];
            unsigned p0 = (o0 != 0xFFFFu) ? Epack[o0 + t] : 0u;
            unsigned p1v = (o1 != 0xFFFFu) ? Epack[o1 + t] : 0u;
            dh[jp] = (p0 >> 16) | (p1v & 0xFFFF0000u);
            dl[jp] = (p0 << 16 >> 16) | (p1v << 16);
        }
        *(uint4*)&XhiL[t*40 + c4*8] = make_uint4(dh[0], dh[1], dh[2], dh[3]);
        *(uint4*)&XloL[t*40 + c4*8] = make_uint4(dl[0], dl[1], dl[2], dl[3]);
    }
    __syncthreads();                        // Xt(0) ready

    for (int kc = 0; kc < 9; ++kc) {
        // prefetch A-frags for kc+1 (registers; waits overlap MFMA below)
        short8 ahN[3], alN[3];
        if (kc + 1 < 9) {
            #pragma unroll
            for (int m = 0; m < 3; ++m) {
                ahN[m] = *(const short8*)&ahP[m][(kc+1)*32];
                alN[m] = *(const short8*)&alP[m][(kc+1)*32];
            }
        }
        // MFMA on chunk kc
        #pragma unroll
        for (int nf = 0; nf < 4; ++nf) {
            int tn = (ng*4 + nf)*16 + r16;
            short8 bh = *(const short8*)&XhiL[tn*40 + q*8];
            short8 bl = *(const short8*)&XloL[tn*40 + q*8];
            #pragma unroll
            for (int m = 0; m < 3; ++m) {
                acc[m][nf] = __builtin_amdgcn_mfma_f32_16x16x32_bf16(ahC[m], bh, acc[m][nf], 0, 0, 0);
                acc[m][nf] = __builtin_amdgcn_mfma_f32_16x16x32_bf16(ahC[m], bl, acc[m][nf], 0, 0, 0);
                acc[m][nf] = __builtin_amdgcn_mfma_f32_16x16x32_bf16(alC[m], bh, acc[m][nf], 0, 0, 0);
            }
        }
        if (kc + 1 < 9) {
            __syncthreads();                // Xt(kc) consumed block-wide
            #pragma unroll
            for (int s = 0; s < 2; ++s) {
                int u = tid + s*256;
                int t = u >> 2, c4 = u & 3;
                const unsigned short* ct = &ctab[(kc+1)*32 + c4*8];
                unsigned dh[4], dl[4];
                #pragma unroll
                for (int jp = 0; jp < 4; ++jp) {
                    unsigned short o0 = ct[2*jp], o1 = ct[2*jp+1];
                    unsigned p0 = (o0 != 0xFFFFu) ? Epack[o0 + t] : 0u;
                    unsigned p1v = (o1 != 0xFFFFu) ? Epack[o1 + t] : 0u;
                    dh[jp] = (p0 >> 16) | (p1v & 0xFFFF0000u);
                    dl[jp] = (p0 << 16 >> 16) | (p1v << 16);
                }
                *(uint4*)&XhiL[t*40 + c4*8] = make_uint4(dh[0], dh[1], dh[2], dh[3]);
                *(uint4*)&XloL[t*40 + c4*8] = make_uint4(dl[0], dl[1], dl[2], dl[3]);
            }
            __syncthreads();                // Xt(kc+1) ready
            #pragma unroll
            for (int m = 0; m < 3; ++m) { ahC[m] = ahN[m]; alC[m] = alN[m]; }
        }
    }

    // epilogue: C/D col=lane&15 (t), row=q*4+reg (o). Store + BN2 partials.
    float* h2b = h2 + (size_t)b*C2*TSTR;
    float* pb = part2 + (((size_t)b*NT8 + tile)*2 + ng)*192;
    #pragma unroll
    for (int m = 0; m < 3; ++m) {
        float s[4] = {0.f, 0.f, 0.f, 0.f}, s2[4] = {0.f, 0.f, 0.f, 0.f};
        #pragma unroll
        for (int nf = 0; nf < 4; ++nf) {
            int t = t0 + (ng*4 + nf)*16 + r16;
            bool ok = t < TOUT;
            #pragma unroll
            for (int reg = 0; reg < 4; ++reg) {
                float v = acc[m][nf][reg];
                if (ok) {
                    int o = mg*48 + m*16 + q*4 + reg;
                    h2b[(size_t)o*TSTR + t] = v;
                    s[reg] += v; s2[reg] += v*v;
                }
            }
        }
        #pragma unroll
        for (int reg = 0; reg < 4; ++reg) {
            float a = s[reg], b2 = s2[reg];
            #pragma unroll
            for (int d = 8; d > 0; d >>= 1) {
                a  += __shfl_down(a,  d, 16);
                b2 += __shfl_down(b2, d, 16);
            }
            if (r16 == 0) {
                int o = mg*48 + m*16 + q*4 + reg;
                pb[o] = a; pb[96 + o] = b2;
            }
        }
    }
}

// ================= K4: finalize BN2 params (1 block / channel) ==========
__global__ __launch_bounds__(256) void k4_bn2(const float* __restrict__ part2,
        const float* __restrict__ g, const float* __restrict__ bta, float* __restrict__ p2) {
    __shared__ float rs[4], rs2[4];
    int q = blockIdx.x, t = threadIdx.x;
    float s = 0.f, s2 = 0.f;
    for (int blk = t; blk < NPART; blk += 256) {
        s  += part2[(size_t)blk*192 + q];
        s2 += part2[(size_t)blk*192 + 96 + q];
    }
    for (int off = 32; off > 0; off >>= 1) {
        s  += __shfl_down(s,  off, 64);
        s2 += __shfl_down(s2, off, 64);
    }
    int lane = t & 63, wv = t >> 6;
    if (lane == 0) { rs[wv] = s; rs2[wv] = s2; }
    __syncthreads();
    if (t == 0) {
        double S  = (double)rs[0]  + rs[1]  + rs[2]  + rs[3];
        double S2 = (double)rs2[0] + rs2[1] + rs2[2] + rs2[3];
        double N = (double)BSZ * (double)TOUT;
        double mu = S / N, var = S2 / N - mu*mu;
        double scale = (double)g[q] / sqrt(var + 1e-5);
        p2[q] = (float)scale;
        p2[C2 + q] = (float)((double)bta[q] - mu*scale);
    }
}

// ===== K5 v2: Gram, 4x4 tiles, wave-private staging, no inner barriers ==========
__global__ __launch_bounds__(256) void k5_gram(const float* __restrict__ h2,
        const float* __restrict__ p2, float* __restrict__ S) {
    __shared__ float smem[4*2176];          // per-wave [32][68]; overlaid red [64][17]
    int bm = blockIdx.x;
    int b = bm / 3, m = bm % 3;
    int tid = threadIdx.x;
    int w = tid >> 6, lane = tid & 63;
    float* sx = smem + w*2176;
    const float* hb = h2 + ((size_t)b*C2 + m*32)*TSTR;
    int srow = lane >> 1;
    int scol = (lane & 1) * 32;
    float sc = p2[m*32 + srow], sh = p2[C2 + m*32 + srow];
    int r0 = (lane >> 3) << 2, c0 = (lane & 7) << 2;
    float acc[4][4];
    #pragma unroll
    for (int i = 0; i < 4; ++i)
        #pragma unroll
        for (int j = 0; j < 4; ++j) acc[i][j] = 0.f;

    for (int t0 = w*64; t0 < TOUT; t0 += 256) {
        const float* src = &hb[(size_t)srow*TSTR + t0 + scol];
        float* drow = &sx[srow*68 + scol];
        if (t0 + 63 < TOUT) {
            #pragma unroll
            for (int j = 0; j < 8; ++j) {
                float4 xv = *(const float4*)&src[4*j];
                float4 v;
                v.x = elu_f(fmaf(xv.x, sc, sh));
                v.y = elu_f(fmaf(xv.y, sc, sh));
                v.z = elu_f(fmaf(xv.z, sc, sh));
                v.w = elu_f(fmaf(xv.w, sc, sh));
                *(float4*)&drow[4*j] = v;
            }
        } else {
            #pragma unroll
            for (int j = 0; j < 8; ++j) {
                float4 xv = *(const float4*)&src[4*j];
                int tb = t0 + scol + 4*j;
                float4 v;
                v.x = (tb + 0 < TOUT) ? elu_f(fmaf(xv.x, sc, sh)) : 0.f;
                v.y = (tb + 1 < TOUT) ? elu_f(fmaf(xv.y, sc, sh)) : 0.f;
                v.z = (tb + 2 < TOUT) ? elu_f(fmaf(xv.z, sc, sh)) : 0.f;
                v.w = (tb + 3 < TOUT) ? elu_f(fmaf(xv.w, sc, sh)) : 0.f;
                *(float4*)&drow[4*j] = v;
            }
        }
        #pragma unroll
        for (int tc = 0; tc < 16; ++tc) {
            float4 a0 = *(const float4*)&sx[(r0+0)*68 + tc*4];
            float4 a1 = *(const float4*)&sx[(r0+1)*68 + tc*4];
            float4 a2 = *(const float4*)&sx[(r0+2)*68 + tc*4];
            float4 a3 = *(const float4*)&sx[(r0+3)*68 + tc*4];
            float4 b0 = *(const float4*)&sx[(c0+0)*68 + tc*4];
            float4 b1 = *(const float4*)&sx[(c0+1)*68 + tc*4];
            float4 b2 = *(const float4*)&sx[(c0+2)*68 + tc*4];
            float4 b3 = *(const float4*)&sx[(c0+3)*68 + tc*4];
            #pragma unroll
            for (int i = 0; i < 4; ++i) {
                float4 ai = (i == 0) ? a0 : (i == 1) ? a1 : (i == 2) ? a2 : a3;
                acc[i][0] = fmaf(ai.x, b0.x, fmaf(ai.y, b0.y, fmaf(ai.z, b0.z, fmaf(ai.w, b0.w, acc[i][0]))));
                acc[i][1] = fmaf(ai.x, b1.x, fmaf(ai.y, b1.y, fmaf(ai.z, b1.z, fmaf(ai.w, b1.w, acc[i][1]))));
                acc[i][2] = fmaf(ai.x, b2.x, fmaf(ai.y, b2.y, fmaf(ai.z, b2.z, fmaf(ai.w, b2.w, acc[i][2]))));
                acc[i][3] = fmaf(ai.x, b3.x, fmaf(ai.y, b3.y, fmaf(ai.z, b3.z, fmaf(ai.w, b3.w, acc[i][3]))));
            }
        }
    }

    float* red = smem + w*2176;
    #pragma unroll
    for (int i = 0; i < 4; ++i)
        #pragma unroll
        for (int j = 0; j < 4; ++j)
            red[lane*17 + i*4 + j] = acc[i][j];
    __syncthreads();
    int e0 = tid * 4;
    int r = e0 >> 5, c = e0 & 31;
    int tl = (r >> 2)*8 + (c >> 2);
    int sb = (r & 3)*4;
    float o0 = 0.f, o1 = 0.f, o2 = 0.f, o3 = 0.f;
    #pragma unroll
    for (int ww = 0; ww < 4; ++ww) {
        const float* rp = smem + ww*2176 + tl*17 + sb;
        o0 += rp[0]; o1 += rp[1]; o2 += rp[2]; o3 += rp[3];
    }
    float* Sb2 = S + (size_t)bm*1024;
    *(float4*)&Sb2[e0] = make_float4(o0, o1, o2, o3);
}

// ===== K6 v11: v9 layouts EXACTLY (A stride 35, Vt[32][34] float2) + packed tables ====
// Post-mortem v10: Vt b32-transpose REGRESSED (113.8->118.7us, conflicts
// 1.72e7->1.94e7) -- v9's b64 Vt at rr*34+2kk was already near-optimal (16
// distinct rr -> 16 distinct even banks lo-dword, odd hi-dword); splitting to
// b32 doubled V-path LDS ops and added cross-group collisions. v10 bundled two
// changes; the packed-table addressing was the good half (VALUBusy 51->49.7).
// v11 = v9 bit-identical memory access pattern + ONLY the packed tables:
// ptabR = p*35|(q*35)<<16, ptabC = rr|ss<<5|(rr*35)<<10|(ss*35)<<21; Vt
// offsets derived rr34 = rr35 - rr (sub, not mul). ~20-25 VALU/round saved.
__device__ __forceinline__ void pair_of(int r, int k, int& p, int& q) {
    if (k == 0) { p = r; q = 31; }
    else {
        int a = (r + k) % 31;
        int b2 = (r - k + 31) % 31;
        p = min(a, b2); q = max(a, b2);
    }
}

__device__ __forceinline__ void jacobi_cs(float app, float aqq, float apq,
                                          float& c, float& s) {
    c = 1.f; s = 0.f;
    if (apq != 0.f) {
        float tau = (aqq - app) * 0.5f * __builtin_amdgcn_rcpf(apq);
        float sq  = __builtin_amdgcn_sqrtf(fmaf(tau, tau, 1.f));
        float tt  = (tau >= 0.f ? 1.f : -1.f) * __builtin_amdgcn_rcpf(fabsf(tau) + sq);
        c = __builtin_amdgcn_rsqf(fmaf(tt, tt, 1.f));
        s = tt * c;
        if (!(c == c) || !(s == s)) { c = 1.f; s = 0.f; }
    }
}

// one Jacobi round: read AF/VF (state), write AT/VT (next), 1 barrier.
// A* flat stride 35; V* flat stride 34 (= v9's Vt[32][34], float2 ops).
#define J_ROUND(RR_, AF, AT, VF, VT) do {                                   \
    int base_ = (RR_) << 4;                                                 \
    unsigned tr_ = ptabR[base_ + kk_];                                      \
    unsigned tc_ = ptabC[base_ + ll_];                                      \
    int p35_ = tr_ & 0xffff, q35_ = (int)(tr_ >> 16);                       \
    int rr_ = tc_ & 31, ss_ = (tc_ >> 5) & 31;                              \
    int rr35_ = (tc_ >> 10) & 2047, ss35_ = (int)(tc_ >> 21);               \
    int rr34_ = rr35_ - rr_, ss34_ = ss35_ - ss_;                           \
    float brr_ = AF[rr35_ + rr_], bss_ = AF[ss35_ + ss_], brs_ = AF[rr35_ + ss_]; \
    float apr_ = AF[p35_ + rr_], aps_ = AF[p35_ + ss_];                     \
    float aqr_ = AF[q35_ + rr_], aqs_ = AF[q35_ + ss_];                     \
    float2 vr_ = *(const float2*)&VF[rr34_ + i0];                           \
    float2 vs_ = *(const float2*)&VF[ss34_ + i0];                           \
    float cl_, sl_;                                                         \
    jacobi_cs(brr_, bss_, brs_, cl_, sl_);                                  \
    float ck_ = __shfl(cl_, kk_, 64);                                       \
    float sk_ = __shfl(sl_, kk_, 64);                                       \
    float tpr_ = ck_*apr_ - sk_*aqr_;                                       \
    float tqr_ = sk_*apr_ + ck_*aqr_;                                       \
    float tps_ = ck_*aps_ - sk_*aqs_;                                       \
    float tqs_ = sk_*aps_ + ck_*aqs_;                                       \
    AT[p35_ + rr_] = cl_*tpr_ - sl_*tps_;                                   \
    AT[p35_ + ss_] = sl_*tpr_ + cl_*tps_;                                   \
    AT[q35_ + rr_] = cl_*tqr_ - sl_*tqs_;                                   \
    AT[q35_ + ss_] = sl_*tqr_ + cl_*tqs_;                                   \
    float2 nvr_, nvs_;                                                      \
    nvr_.x = cl_*vr_.x - sl_*vs_.x;                                         \
    nvr_.y = cl_*vr_.y - sl_*vs_.y;                                         \
    nvs_.x = sl_*vr_.x + cl_*vs_.x;                                         \
    nvs_.y = sl_*vr_.y + cl_*vs_.y;                                         \
    *(float2*)&VT[rr34_ + i0] = nvr_;                                       \
    *(float2*)&VT[ss34_ + i0] = nvs_;                                       \
    __syncthreads();                                                        \
} while (0)

__global__ __launch_bounds__(256) void k6_eig(const float* __restrict__ S,
        const float* __restrict__ wq, const float* __restrict__ wk, const float* __restrict__ wv,
        float* __restrict__ QQt, float* __restrict__ KKt, float* __restrict__ Vp) {
    __shared__ float A0[32*35], A1[32*35];   // flat, stride 35 (v9 layout)
    __shared__ float V0[32*34], V1[32*34];   // flat, stride 34 = v9 Vt[32][34]
    __shared__ float sW[3][512];
    __shared__ unsigned int ptabR[31*16];    // (p*35) | (q*35)<<16
    __shared__ unsigned int ptabC[31*16];    // rr | ss<<5 | (rr*35)<<10 | (ss*35)<<21
    __shared__ float Up[32][9];
    __shared__ float Aw[16][9];
    __shared__ float G[8][9];
    __shared__ float Lm[8][9];
    __shared__ float Mm[16][9];
    __shared__ float lam[32];
    int bm = blockIdx.x, b = bm / 3, m = bm % 3;
    int tid = threadIdx.x;
    const float* Sb = S + (size_t)bm*1024;
    for (int i = tid; i < 1024; i += 256) {
        int r_ = i >> 5, c_ = i & 31;
        A0[r_*35 + c_] = Sb[i];
        V0[r_*34 + c_] = (r_ == c_) ? 1.f : 0.f;
    }
    for (int i = tid; i < 512; i += 256) {
        sW[0][i] = wq[i]; sW[1][i] = wk[i]; sW[2][i] = wv[i];
    }
    for (int i = tid; i < 31*16; i += 256) {
        int r_ = i >> 4, k_ = i & 15;
        int p, q; pair_of(r_, k_, p, q);
        ptabR[i] = (unsigned)(p*35) | ((unsigned)(q*35) << 16);
        ptabC[i] = (unsigned)p | ((unsigned)q << 5)
                 | ((unsigned)(p*35) << 10) | ((unsigned)(q*35) << 21);
    }
    __syncthreads();

    int kk_ = tid >> 4, ll_ = tid & 15;     // task: row-pair kk_ x col-pair ll_
    int i0 = kk_ * 2;                       // Vt column chunk for this task
    // 155 rounds = 77 statically-unrolled pairs (buf0->buf1->buf0) + 1 tail.
    int r = 0;
    for (int gp = 0; gp < 77; ++gp) {
        J_ROUND(r, A0, A1, V0, V1);
        r = (r + 1 == 31) ? 0 : r + 1;
        J_ROUND(r, A1, A0, V1, V0);
        r = (r + 1 == 31) ? 0 : r + 1;
    }
    J_ROUND(r, A0, A1, V0, V1);             // round 155: final state in A1/V1

    // top-8 eigenvalue selection (descending) -> Up (Up[row][rank] = V1[col][row])
    if (tid < 32) lam[tid] = A1[tid*36];    // tid*35 + tid
    __syncthreads();
    if (tid < 32) {
        float lj = lam[tid];
        int rank = 0;
        #pragma unroll
        for (int i = 0; i < 32; ++i) {
            float li = lam[i];
            rank += (li > lj) || (li == lj && i < tid);
        }
        if (rank < PDIM) {
            #pragma unroll
            for (int i = 0; i < 32; ++i) Up[i][rank] = V1[tid*34 + i];
        }
    }
    __syncthreads();

    // projections: P = A (A^T A)^{-1} A^T for A = W * Up  (== qr(A).Q @ Q^T)
    for (int widx = 0; widx < 3; ++widx) {
        if (widx == 2 && m != 2) break;   // V-projection only needed for m==2
        const float* W = sW[widx];
        if (tid < 128) {
            int o = tid >> 3, pp = tid & 7;
            float s = 0.f;
            #pragma unroll
            for (int i = 0; i < 32; ++i) s = fmaf(W[o*32 + i], Up[i][pp], s);
            Aw[o][pp] = s;
        }
        __syncthreads();
        if (tid < 64) {
            int xx = tid >> 3, yy = tid & 7;
            float s = 0.f;
            #pragma unroll
            for (int o = 0; o < 16; ++o) s = fmaf(Aw[o][xx], Aw[o][yy], s);
            G[xx][yy] = s;
        }
        __syncthreads();
        if (tid == 0) {
            float Lr[8][8];
            #pragma unroll
            for (int jj = 0; jj < 8; ++jj) {
                float d = G[jj][jj];
                #pragma unroll
                for (int kk2 = 0; kk2 < 8; ++kk2) if (kk2 < jj) d -= Lr[jj][kk2]*Lr[jj][kk2];
                d = sqrtf(fmaxf(d, 1e-30f));
                float inv = 1.f / d;
                Lr[jj][jj] = d;
                Lm[jj][jj] = inv;     // store INVERSE of diagonal
                #pragma unroll
                for (int ii = 0; ii < 8; ++ii) if (ii > jj) {
                    float v = G[ii][jj];
                    #pragma unroll
                    for (int kk2 = 0; kk2 < 8; ++kk2) if (kk2 < jj) v -= Lr[ii][kk2]*Lr[jj][kk2];
                    v *= inv;
                    Lr[ii][jj] = v;
                    Lm[ii][jj] = v;
                }
            }
        }
        __syncthreads();
        if (tid < 16) {
            int o = tid;
            float a[8], mv[8];
            #pragma unroll
            for (int pp = 0; pp < 8; ++pp) a[pp] = Aw[o][pp];
            #pragma unroll
            for (int jj = 0; jj < 8; ++jj) {
                float v = a[jj];
                #pragma unroll
                for (int kk2 = 0; kk2 < 8; ++kk2) if (kk2 < jj) v -= Lm[jj][kk2]*mv[kk2];
                mv[jj] = v * Lm[jj][jj];
            }
            #pragma unroll
            for (int pp = 0; pp < 8; ++pp) Mm[o][pp] = mv[pp];
        }
        __syncthreads();
        {
            int d = tid >> 4, e = tid & 15;
            float s = 0.f;
            #pragma unroll
            for (int pp = 0; pp < 8; ++pp) s = fmaf(Mm[d][pp], Mm[e][pp], s);
            float* dst = (widx == 0) ? (QQt + (size_t)bm*256)
                       : (widx == 1) ? (KKt + (size_t)bm*256)
                       : (Vp + (size_t)b*256);
            dst[d*16 + e] = s;
        }
        __syncthreads();
    }
}

// ================= K7: attention scores + softmax(i=2) + output linear ==========
__global__ __launch_bounds__(64) void k7_out(const float* __restrict__ QQt,
        const float* __restrict__ KKt, const float* __restrict__ Vp,
        const float* __restrict__ lw, const float* __restrict__ lb,
        float* __restrict__ out) {
    __shared__ float sQ[3][256], sK[3][256], sVp[256], ssc[9], wj[3];
    int b = blockIdx.x, tid = threadIdx.x;
    for (int i = tid; i < 768; i += 64) {
        sQ[i >> 8][i & 255] = QQt[(size_t)b*768 + i];
        sK[i >> 8][i & 255] = KKt[(size_t)b*768 + i];
    }
    for (int i = tid; i < 256; i += 64) sVp[i] = Vp[(size_t)b*256 + i];
    __syncthreads();
    for (int pair = 0; pair < 9; ++pair) {
        int i = pair / 3, j = pair % 3;
        const float* Qj = sQ[j];
        const float* Ki = sK[i];
        float accp = 0.f;
        #pragma unroll
        for (int it = 0; it < 4; ++it) {
            int e = tid + 64*it;
            int d = e >> 4, ee = e & 15;
            float y = 0.f;
            #pragma unroll
            for (int f = 0; f < 16; ++f) {
                float dv = Qj[d*16 + f] - Ki[d*16 + f];
                float ev = Qj[ee*16 + f] - Ki[ee*16 + f];
                y = fmaf(dv, ev, y);
            }
            accp += y*y;
        }
        for (int off = 32; off > 0; off >>= 1) accp += __shfl_down(accp, off, 64);
        if (tid == 0) {
            float E = sqrtf(accp);
            ssc[pair] = 1.f / (1.f + log1pf(E));
        }
        __syncthreads();
    }
    if (tid < 3) {
        int j = tid;
        float e0 = expf(ssc[0*3 + j]), e1 = expf(ssc[1*3 + j]), e2 = expf(ssc[2*3 + j]);
        wj[j] = e2 / (e0 + e1 + e2);
    }
    __syncthreads();
    int o = tid >> 4, g = tid & 15;
    float part = 0.f;
    #pragma unroll
    for (int t = 0; t < 16; ++t) {
        int de = g*16 + t;
        float vv = sVp[de];
        float l0 = lw[o*768 + de];
        float l1 = lw[o*768 + 256 + de];
        float l2 = lw[o*768 + 512 + de];
        part = fmaf(vv, fmaf(wj[0], l0, fmaf(wj[1], l1, wj[2]*l2)), part);
    }
    for (int off = 8; off > 0; off >>= 1) part += __shfl_down(part, off, 16);
    if (g == 0) out[b*4 + o] = part + lb[o];
}

// ================= launch ==========
extern "C" void kernel_launch(void* const* d_in, const int* in_sizes, int n_in,
                              void* d_out, int out_size, void* d_ws, size_t ws_size,
                              hipStream_t stream) {
    const float* x  = (const float*)d_in[0];
    const float* w1 = (const float*)d_in[1];
    // d_in[2] conv1_b: cancels exactly in batch-norm (mean subtraction) -> unused
    const float* g1 = (const float*)d_in[3];
    const float* b1 = (const float*)d_in[4];
    const float* w2 = (const float*)d_in[5];
    // d_in[6] conv2_b: cancels exactly in batch-norm -> unused
    const float* g2 = (const float*)d_in[7];
    const float* b2 = (const float*)d_in[8];
    const float* wq = (const float*)d_in[9];
    const float* wk = (const float*)d_in[10];
    const float* wv = (const float*)d_in[11];
    const float* lw = (const float*)d_in[12];
    const float* lb = (const float*)d_in[13];

    float* ws   = (float*)d_ws;
    float* h1   = ws + OFF_H1;
    float* h2   = ws + OFF_H2;
    float* Sm   = ws + OFF_S;
    unsigned short* WhiG = (unsigned short*)(ws + OFF_WH);
    unsigned short* WloG = (unsigned short*)(ws + OFF_WL);
    float* qqt  = ws + OFF_QQT;
    float* kkt  = ws + OFF_KKT;
    float* vpm  = ws + OFF_VP;
    float* p1a  = ws + OFF_P1;
    float* p2a  = ws + OFF_P2;
    float* bn1p = ws + OFF_BN1;
    float* bn2p = ws + OFF_BN2;

    k0_wsplit<<<(96*288 + 255)/256, 256, 0, stream>>>(w2, WhiG, WloG);
    k1_conv1<<<BSZ, 256, 0, stream>>>(x, w1, h1, p1a);
    k2_bn1<<<CEEG, 64, 0, stream>>>(p1a, g1, b1, bn1p);
    dim3 g3(BSZ, NT8);
    k3_conv2<<<g3, 256, 0, stream>>>(h1, WhiG, WloG, bn1p, h2, p2a);
    k4_bn2<<<C2, 256, 0, stream>>>(p2a, g2, b2, bn2p);
    k5_gram<<<BSZ*3, 256, 0, stream>>>(h2, bn2p, Sm);
    k6_eig<<<BSZ*3, 256, 0, stream>>>(Sm, wq, wk, wv, qqt, kkt, vpm);
    k7_out<<<BSZ, 64, 0, stream>>>(qqt, kkt, vpm, lw, lb, (float*)d_out);
}

// Round 9
// 367.962 us; speedup vs baseline: 1.0666x; 1.0666x over previous
//
#include <hip/hip_runtime.h>
#include <math.h>

#define PDIM 8
#define BSZ 256
#define CEEG 22
#define TLEN 1000
#define KW 12
#define C2 96
#define TOUT 989
#define TSTR 992          // padded h2 row stride (16B-aligned float4 stores)
#define NSWEEP 5          // 4 FAILS (absmax 3.6e-2); 5 = machine floor. LOCKED.
#define NT8 8             // k3 t-tiles of 128
#define NPART (BSZ*NT8*2) // BN2 stat partial groups (2 n-groups per tile)

typedef __attribute__((ext_vector_type(8))) short short8;
typedef __attribute__((ext_vector_type(4))) float floatx4;

// ---- workspace layout (in floats) ----
#define OFF_H1   ((size_t)0)
#define SZ_H1    ((size_t)BSZ*CEEG*TLEN)
#define OFF_H2   (OFF_H1 + SZ_H1)
#define SZ_H2    ((size_t)BSZ*C2*TSTR)
#define OFF_S    (OFF_H2 + SZ_H2)
#define SZ_S     ((size_t)BSZ*3*1024)
// Whi/Wlo (bf16, 96x288 each) ALIAS the S region: written by k0w, consumed by
// k3, then S is (re)written later by k5. No lifetime overlap.
#define OFF_WH   (OFF_S)
#define OFF_WL   (OFF_S + (size_t)13824)
#define OFF_QQT  (OFF_S + SZ_S)
#define SZ_QQT   ((size_t)BSZ*3*256)
#define OFF_KKT  (OFF_QQT + SZ_QQT)
#define OFF_VP   (OFF_KKT + SZ_QQT)
#define SZ_VP    ((size_t)BSZ*256)
#define OFF_P1   (OFF_VP + SZ_VP)
#define SZ_P1    ((size_t)BSZ*44)
#define OFF_P2   (OFF_P1 + SZ_P1)
#define SZ_P2    ((size_t)NPART*192)
#define OFF_BN1  (OFF_P2 + SZ_P2)
#define OFF_BN2  (OFF_BN1 + (size_t)64)

__device__ __forceinline__ float elu_f(float z) { return z > 0.f ? z : expm1f(z); }

__device__ __forceinline__ unsigned short f2bf(float x) {
    unsigned u = __float_as_uint(x);
    u += 0x7fffu + ((u >> 16) & 1u);
    return (unsigned short)(u >> 16);
}
__device__ __forceinline__ float bf2f(unsigned short h) {
    return __uint_as_float(((unsigned)h) << 16);
}

// ================= K0w: precompute split-bf16 weights Whi/Wlo [96][288] ==========
__global__ __launch_bounds__(256) void k0_wsplit(const float* __restrict__ w2,
        unsigned short* __restrict__ Whi, unsigned short* __restrict__ Wlo) {
    int i = blockIdx.x*256 + threadIdx.x;
    if (i >= 96*288) return;
    int o = i / 288, kap = i - o*288;
    float v = (kap < 264) ? w2[o*264 + kap] : 0.f;
    unsigned short h = f2bf(v);
    float lo = v - bf2f(h);
    Whi[i] = h;
    Wlo[i] = f2bf(lo);
}

// ================= K1: conv1 (22ch spatial filter) + BN1 partial stats ==========
__global__ __launch_bounds__(256) void k1_conv1(const float* __restrict__ x,
        const float* __restrict__ w1, float* __restrict__ h1,
        float* __restrict__ part1) {
    __shared__ float sw[CEEG*CEEG];       // [o][c]
    __shared__ float red[4][44];
    int b = blockIdx.x;
    int tid = threadIdx.x;
    for (int i = tid; i < CEEG*CEEG; i += 256) sw[i] = w1[i];
    __syncthreads();
    float sum[CEEG], sumsq[CEEG];
    #pragma unroll
    for (int o = 0; o < CEEG; ++o) { sum[o] = 0.f; sumsq[o] = 0.f; }
    const float* xb = x + (size_t)b*CEEG*TLEN;
    float* hb = h1 + (size_t)b*CEEG*TLEN;
    for (int it = 0; it < 4; ++it) {
        int t = it*256 + tid;
        if (t < TLEN) {
            float acc[CEEG];
            #pragma unroll
            for (int o = 0; o < CEEG; ++o) acc[o] = 0.f;
            #pragma unroll 2
            for (int c = 0; c < CEEG; ++c) {
                float xv = xb[c*TLEN + t];
                #pragma unroll
                for (int o = 0; o < CEEG; ++o) acc[o] = fmaf(xv, sw[o*CEEG + c], acc[o]);
            }
            #pragma unroll
            for (int o = 0; o < CEEG; ++o) {
                hb[o*TLEN + t] = acc[o];
                sum[o]  += acc[o];
                sumsq[o] += acc[o]*acc[o];
            }
        }
    }
    int lane = tid & 63, wv = tid >> 6;
    #pragma unroll
    for (int o = 0; o < CEEG; ++o) {
        float s = sum[o], s2 = sumsq[o];
        for (int off = 32; off > 0; off >>= 1) {
            s  += __shfl_down(s,  off, 64);
            s2 += __shfl_down(s2, off, 64);
        }
        if (lane == 0) { red[wv][o] = s; red[wv][CEEG + o] = s2; }
    }
    __syncthreads();
    if (tid < 44) {
        part1[(size_t)b*44 + tid] = red[0][tid] + red[1][tid] + red[2][tid] + red[3][tid];
    }
}

// ================= K2: finalize BN1 params (1 block / channel) ==========
__global__ __launch_bounds__(64) void k2_bn1(const float* __restrict__ part1,
        const float* __restrict__ g, const float* __restrict__ bta, float* __restrict__ p1) {
    int c = blockIdx.x, t = threadIdx.x;
    float s = 0.f, s2 = 0.f;
    for (int blk = t; blk < BSZ; blk += 64) {
        s  += part1[(size_t)blk*44 + c];
        s2 += part1[(size_t)blk*44 + CEEG + c];
    }
    for (int off = 32; off > 0; off >>= 1) {
        s  += __shfl_down(s,  off, 64);
        s2 += __shfl_down(s2, off, 64);
    }
    if (t == 0) {
        double N = (double)BSZ * (double)TLEN;
        double mu = (double)s / N, var = (double)s2 / N - mu*mu;
        double scale = (double)g[c] / sqrt(var + 1e-5);
        p1[c] = (float)scale;
        p1[CEEG + c] = (float)((double)bta[c] - mu*scale);
    }
}

// ===== K3 v8: split-bf16 MFMA GEMM, 256 thr, packed-E (hi|lo u32) Xt build ====
// C[96][128] = W[96][288] x X[288][128]. Waves: mg = w&1 (o half), ng = w>>1
// (t half). A-frags: global->register direct, double-buffered. E packed as
// u32 (hi16<<16)|(lo16 trunc) once; Xt build is pure bit-ops.
__global__ __launch_bounds__(256) void k3_conv2(const float* __restrict__ h1,
        const unsigned short* __restrict__ WhiG, const unsigned short* __restrict__ WloG,
        const float* __restrict__ p1, float* __restrict__ h2, float* __restrict__ part2) {
    __shared__ unsigned Epack[22*152];      // (hi16<<16)|(lo16), [c][tt<139]
    __shared__ unsigned short ctab[288];    // kappa -> E offset (c*152+k), 0xFFFF = pad
    __shared__ short XhiL[128*40];          // Xt chunk [t][40], 32 used
    __shared__ short XloL[128*40];
    int b = blockIdx.x;
    int tile = blockIdx.y;                  // 0..7
    int t0 = tile * 128;
    int tid = threadIdx.x;
    int lane = tid & 63, w = tid >> 6;
    int r16 = lane & 15, q = lane >> 4;
    int mg = w & 1, ng = w >> 1;
    const float* hb = h1 + (size_t)b*CEEG*TLEN;

    // stage E window [t0, t0+138] with BN1+ELU, packed hi|lo; zero beyond TLEN
    for (int i = tid; i < 22*139; i += 256) {
        int c = i / 139, tt = i - c*139;
        int t = t0 + tt;
        unsigned pk = 0u;
        if (t < TLEN) {
            float v = elu_f(fmaf(hb[c*TLEN + t], p1[c], p1[CEEG + c]));
            unsigned uv = __float_as_uint(v);
            unsigned hi = uv & 0xFFFF0000u;
            float lo = v - __uint_as_float(hi);
            pk = hi | (__float_as_uint(lo) >> 16);
        }
        Epack[c*152 + tt] = pk;
    }
    for (int i = tid; i < 288; i += 256) {
        int c = i / 12, k = i - c*12;
        ctab[i] = (i < 264) ? (unsigned short)(c*152 + k) : (unsigned short)0xFFFF;
    }

    // A-frag row pointers (this lane's 16B segment per m-tile)
    const unsigned short* ahP[3];
    const unsigned short* alP[3];
    #pragma unroll
    for (int m = 0; m < 3; ++m) {
        int row = mg*48 + m*16 + r16;
        ahP[m] = WhiG + row*288 + q*8;
        alP[m] = WloG + row*288 + q*8;
    }
    short8 ahC[3], alC[3];
    #pragma unroll
    for (int m = 0; m < 3; ++m) {
        ahC[m] = *(const short8*)&ahP[m][0];
        alC[m] = *(const short8*)&alP[m][0];
    }

    floatx4 acc[3][4];
    #pragma unroll
    for (int m = 0; m < 3; ++m)
        #pragma unroll
        for (int nf = 0; nf < 4; ++nf) acc[m][nf] = (floatx4){0.f, 0.f, 0.f, 0.f};

    __syncthreads();                        // Epack ready

    // build Xt for chunk 0 (tasks: u -> row u>>2, 16B chunk u&3)
    #pragma unroll
    for (int s = 0; s < 2; ++s) {
        int u = tid + s*256;
        int t = u >> 2, c4 = u & 3;
        const unsigned short* ct = &ctab[c4*8];
        unsigned dh[4], dl[4];
        #pragma unroll
        for (int jp = 0; jp < 4; ++jp) {
            unsigned short o0 = ct[2*jp], o1 = ct[2*jp+1];
            unsigned p0 = (o0 != 0xFFFFu) ? Epack[o0 + t] : 0u;
            unsigned p1v = (o1 != 0xFFFFu) ? Epack[o1 + t] : 0u;
            dh[jp] = (p0 >> 16) | (p1v & 0xFFFF0000u);
            dl[jp] = (p0 << 16 >> 16) | (p1v << 16);
        }
        *(uint4*)&XhiL[t*40 + c4*8] = make_uint4(dh[0], dh[1], dh[2], dh[3]);
        *(uint4*)&XloL[t*40 + c4*8] = make_uint4(dl[0], dl[1], dl[2], dl[3]);
    }
    __syncthreads();                        // Xt(0) ready

    for (int kc = 0; kc < 9; ++kc) {
        // prefetch A-frags for kc+1 (registers; waits overlap MFMA below)
        short8 ahN[3], alN[3];
        if (kc + 1 < 9) {
            #pragma unroll
            for (int m = 0; m < 3; ++m) {
                ahN[m] = *(const short8*)&ahP[m][(kc+1)*32];
                alN[m] = *(const short8*)&alP[m][(kc+1)*32];
            }
        }
        // MFMA on chunk kc
        #pragma unroll
        for (int nf = 0; nf < 4; ++nf) {
            int tn = (ng*4 + nf)*16 + r16;
            short8 bh = *(const short8*)&XhiL[tn*40 + q*8];
            short8 bl = *(const short8*)&XloL[tn*40 + q*8];
            #pragma unroll
            for (int m = 0; m < 3; ++m) {
                acc[m][nf] = __builtin_amdgcn_mfma_f32_16x16x32_bf16(ahC[m], bh, acc[m][nf], 0, 0, 0);
                acc[m][nf] = __builtin_amdgcn_mfma_f32_16x16x32_bf16(ahC[m], bl, acc[m][nf], 0, 0, 0);
                acc[m][nf] = __builtin_amdgcn_mfma_f32_16x16x32_bf16(alC[m], bh, acc[m][nf], 0, 0, 0);
            }
        }
        if (kc + 1 < 9) {
            __syncthreads();                // Xt(kc) consumed block-wide
            #pragma unroll
            for (int s = 0; s < 2; ++s) {
                int u = tid + s*256;
                int t = u >> 2, c4 = u & 3;
                const unsigned short* ct = &ctab[(kc+1)*32 + c4*8];
                unsigned dh[4], dl[4];
                #pragma unroll
                for (int jp = 0; jp < 4; ++jp) {
                    unsigned short o0 = ct[2*jp], o1 = ct[2*jp+1];
                    unsigned p0 = (o0 != 0xFFFFu) ? Epack[o0 + t] : 0u;
                    unsigned p1v = (o1 != 0xFFFFu) ? Epack[o1 + t] : 0u;
                    dh[jp] = (p0 >> 16) | (p1v & 0xFFFF0000u);
                    dl[jp] = (p0 << 16 >> 16) | (p1v << 16);
                }
                *(uint4*)&XhiL[t*40 + c4*8] = make_uint4(dh[0], dh[1], dh[2], dh[3]);
                *(uint4*)&XloL[t*40 + c4*8] = make_uint4(dl[0], dl[1], dl[2], dl[3]);
            }
            __syncthreads();                // Xt(kc+1) ready
            #pragma unroll
            for (int m = 0; m < 3; ++m) { ahC[m] = ahN[m]; alC[m] = alN[m]; }
        }
    }

    // epilogue: C/D col=lane&15 (t), row=q*4+reg (o). Store + BN2 partials.
    float* h2b = h2 + (size_t)b*C2*TSTR;
    float* pb = part2 + (((size_t)b*NT8 + tile)*2 + ng)*192;
    #pragma unroll
    for (int m = 0; m < 3; ++m) {
        float s[4] = {0.f, 0.f, 0.f, 0.f}, s2[4] = {0.f, 0.f, 0.f, 0.f};
        #pragma unroll
        for (int nf = 0; nf < 4; ++nf) {
            int t = t0 + (ng*4 + nf)*16 + r16;
            bool ok = t < TOUT;
            #pragma unroll
            for (int reg = 0; reg < 4; ++reg) {
                float v = acc[m][nf][reg];
                if (ok) {
                    int o = mg*48 + m*16 + q*4 + reg;
                    h2b[(size_t)o*TSTR + t] = v;
                    s[reg] += v; s2[reg] += v*v;
                }
            }
        }
        #pragma unroll
        for (int reg = 0; reg < 4; ++reg) {
            float a = s[reg], b2 = s2[reg];
            #pragma unroll
            for (int d = 8; d > 0; d >>= 1) {
                a  += __shfl_down(a,  d, 16);
                b2 += __shfl_down(b2, d, 16);
            }
            if (r16 == 0) {
                int o = mg*48 + m*16 + q*4 + reg;
                pb[o] = a; pb[96 + o] = b2;
            }
        }
    }
}

// ================= K4: finalize BN2 params (1 block / channel) ==========
__global__ __launch_bounds__(256) void k4_bn2(const float* __restrict__ part2,
        const float* __restrict__ g, const float* __restrict__ bta, float* __restrict__ p2) {
    __shared__ float rs[4], rs2[4];
    int q = blockIdx.x, t = threadIdx.x;
    float s = 0.f, s2 = 0.f;
    for (int blk = t; blk < NPART; blk += 256) {
        s  += part2[(size_t)blk*192 + q];
        s2 += part2[(size_t)blk*192 + 96 + q];
    }
    for (int off = 32; off > 0; off >>= 1) {
        s  += __shfl_down(s,  off, 64);
        s2 += __shfl_down(s2, off, 64);
    }
    int lane = t & 63, wv = t >> 6;
    if (lane == 0) { rs[wv] = s; rs2[wv] = s2; }
    __syncthreads();
    if (t == 0) {
        double S  = (double)rs[0]  + rs[1]  + rs[2]  + rs[3];
        double S2 = (double)rs2[0] + rs2[1] + rs2[2] + rs2[3];
        double N = (double)BSZ * (double)TOUT;
        double mu = S / N, var = S2 / N - mu*mu;
        double scale = (double)g[q] / sqrt(var + 1e-5);
        p2[q] = (float)scale;
        p2[C2 + q] = (float)((double)bta[q] - mu*scale);
    }
}

// ===== K5 v2: Gram, 4x4 tiles, wave-private staging, no inner barriers ==========
__global__ __launch_bounds__(256) void k5_gram(const float* __restrict__ h2,
        const float* __restrict__ p2, float* __restrict__ S) {
    __shared__ float smem[4*2176];          // per-wave [32][68]; overlaid red [64][17]
    int bm = blockIdx.x;
    int b = bm / 3, m = bm % 3;
    int tid = threadIdx.x;
    int w = tid >> 6, lane = tid & 63;
    float* sx = smem + w*2176;
    const float* hb = h2 + ((size_t)b*C2 + m*32)*TSTR;
    int srow = lane >> 1;
    int scol = (lane & 1) * 32;
    float sc = p2[m*32 + srow], sh = p2[C2 + m*32 + srow];
    int r0 = (lane >> 3) << 2, c0 = (lane & 7) << 2;
    float acc[4][4];
    #pragma unroll
    for (int i = 0; i < 4; ++i)
        #pragma unroll
        for (int j = 0; j < 4; ++j) acc[i][j] = 0.f;

    for (int t0 = w*64; t0 < TOUT; t0 += 256) {
        const float* src = &hb[(size_t)srow*TSTR + t0 + scol];
        float* drow = &sx[srow*68 + scol];
        if (t0 + 63 < TOUT) {
            #pragma unroll
            for (int j = 0; j < 8; ++j) {
                float4 xv = *(const float4*)&src[4*j];
                float4 v;
                v.x = elu_f(fmaf(xv.x, sc, sh));
                v.y = elu_f(fmaf(xv.y, sc, sh));
                v.z = elu_f(fmaf(xv.z, sc, sh));
                v.w = elu_f(fmaf(xv.w, sc, sh));
                *(float4*)&drow[4*j] = v;
            }
        } else {
            #pragma unroll
            for (int j = 0; j < 8; ++j) {
                float4 xv = *(const float4*)&src[4*j];
                int tb = t0 + scol + 4*j;
                float4 v;
                v.x = (tb + 0 < TOUT) ? elu_f(fmaf(xv.x, sc, sh)) : 0.f;
                v.y = (tb + 1 < TOUT) ? elu_f(fmaf(xv.y, sc, sh)) : 0.f;
                v.z = (tb + 2 < TOUT) ? elu_f(fmaf(xv.z, sc, sh)) : 0.f;
                v.w = (tb + 3 < TOUT) ? elu_f(fmaf(xv.w, sc, sh)) : 0.f;
                *(float4*)&drow[4*j] = v;
            }
        }
        #pragma unroll
        for (int tc = 0; tc < 16; ++tc) {
            float4 a0 = *(const float4*)&sx[(r0+0)*68 + tc*4];
            float4 a1 = *(const float4*)&sx[(r0+1)*68 + tc*4];
            float4 a2 = *(const float4*)&sx[(r0+2)*68 + tc*4];
            float4 a3 = *(const float4*)&sx[(r0+3)*68 + tc*4];
            float4 b0 = *(const float4*)&sx[(c0+0)*68 + tc*4];
            float4 b1 = *(const float4*)&sx[(c0+1)*68 + tc*4];
            float4 b2 = *(const float4*)&sx[(c0+2)*68 + tc*4];
            float4 b3 = *(const float4*)&sx[(c0+3)*68 + tc*4];
            #pragma unroll
            for (int i = 0; i < 4; ++i) {
                float4 ai = (i == 0) ? a0 : (i == 1) ? a1 : (i == 2) ? a2 : a3;
                acc[i][0] = fmaf(ai.x, b0.x, fmaf(ai.y, b0.y, fmaf(ai.z, b0.z, fmaf(ai.w, b0.w, acc[i][0]))));
                acc[i][1] = fmaf(ai.x, b1.x, fmaf(ai.y, b1.y, fmaf(ai.z, b1.z, fmaf(ai.w, b1.w, acc[i][1]))));
                acc[i][2] = fmaf(ai.x, b2.x, fmaf(ai.y, b2.y, fmaf(ai.z, b2.z, fmaf(ai.w, b2.w, acc[i][2]))));
                acc[i][3] = fmaf(ai.x, b3.x, fmaf(ai.y, b3.y, fmaf(ai.z, b3.z, fmaf(ai.w, b3.w, acc[i][3]))));
            }
        }
    }

    float* red = smem + w*2176;
    #pragma unroll
    for (int i = 0; i < 4; ++i)
        #pragma unroll
        for (int j = 0; j < 4; ++j)
            red[lane*17 + i*4 + j] = acc[i][j];
    __syncthreads();
    int e0 = tid * 4;
    int r = e0 >> 5, c = e0 & 31;
    int tl = (r >> 2)*8 + (c >> 2);
    int sb = (r & 3)*4;
    float o0 = 0.f, o1 = 0.f, o2 = 0.f, o3 = 0.f;
    #pragma unroll
    for (int ww = 0; ww < 4; ++ww) {
        const float* rp = smem + ww*2176 + tl*17 + sb;
        o0 += rp[0]; o1 += rp[1]; o2 += rp[2]; o3 += rp[3];
    }
    float* Sb2 = S + (size_t)bm*1024;
    *(float4*)&Sb2[e0] = make_float4(o0, o1, o2, o3);
}

// ===== K6 v12: v9's LDS instruction stream (2D V, b64) + packed tables for A only ==
// Post-mortem v11: conflicts DOUBLED (1.72e7->3.26e7) with provably identical
// addresses -> instruction selection changed: flat-array float2 access
// `&VF[rr34_+i0]` (opaque runtime offset) lost clang's alignment proof and
// was demoted b64 -> 2x b32, doubling V-path LDS ops. v9's 2D form
// `&V[rr_][i0]` proves rr*136 + kk*8 ≡ 0 mod 8 -> b64. v12: V back to 2D
// arrays exactly as v9 (bit-identical LDS pattern); packed tables ONLY for
// the A side (b32 scalar ops, no alignment concern): ptabR = p*35|(q*35)<<16,
// ptabC = rr|ss<<5|(rr*35)<<10|(ss*35)<<21. Saves the x35/x36 index
// multiplies (~15-20 VALU/round/thread), zero LDS-width change.
__device__ __forceinline__ void pair_of(int r, int k, int& p, int& q) {
    if (k == 0) { p = r; q = 31; }
    else {
        int a = (r + k) % 31;
        int b2 = (r - k + 31) % 31;
        p = min(a, b2); q = max(a, b2);
    }
}

__device__ __forceinline__ void jacobi_cs(float app, float aqq, float apq,
                                          float& c, float& s) {
    c = 1.f; s = 0.f;
    if (apq != 0.f) {
        float tau = (aqq - app) * 0.5f * __builtin_amdgcn_rcpf(apq);
        float sq  = __builtin_amdgcn_sqrtf(fmaf(tau, tau, 1.f));
        float tt  = (tau >= 0.f ? 1.f : -1.f) * __builtin_amdgcn_rcpf(fabsf(tau) + sq);
        c = __builtin_amdgcn_rsqf(fmaf(tt, tt, 1.f));
        s = tt * c;
        if (!(c == c) || !(s == s)) { c = 1.f; s = 0.f; }
    }
}

// one Jacobi round: read AF/VF (state), write AT/VT (next), 1 barrier.
// A* flat stride 35 (table offsets); V* 2D [32][34] (b64-provable, v9 form).
#define J_ROUND(RR_, AF, AT, VF, VT) do {                                   \
    int base_ = (RR_) << 4;                                                 \
    unsigned tr_ = ptabR[base_ + kk_];                                      \
    unsigned tc_ = ptabC[base_ + ll_];                                      \
    int p35_ = tr_ & 0xffff, q35_ = (int)(tr_ >> 16);                       \
    int rr_ = tc_ & 31, ss_ = (tc_ >> 5) & 31;                              \
    int rr35_ = (tc_ >> 10) & 2047, ss35_ = (int)(tc_ >> 21);               \
    float brr_ = AF[rr35_ + rr_], bss_ = AF[ss35_ + ss_], brs_ = AF[rr35_ + ss_]; \
    float apr_ = AF[p35_ + rr_], aps_ = AF[p35_ + ss_];                     \
    float aqr_ = AF[q35_ + rr_], aqs_ = AF[q35_ + ss_];                     \
    float2 vr_ = *(const float2*)&VF[rr_][i0];                              \
    float2 vs_ = *(const float2*)&VF[ss_][i0];                              \
    float cl_, sl_;                                                         \
    jacobi_cs(brr_, bss_, brs_, cl_, sl_);                                  \
    float ck_ = __shfl(cl_, kk_, 64);                                       \
    float sk_ = __shfl(sl_, kk_, 64);                                       \
    float tpr_ = ck_*apr_ - sk_*aqr_;                                       \
    float tqr_ = sk_*apr_ + ck_*aqr_;                                       \
    float tps_ = ck_*aps_ - sk_*aqs_;                                       \
    float tqs_ = sk_*aps_ + ck_*aqs_;                                       \
    AT[p35_ + rr_] = cl_*tpr_ - sl_*tps_;                                   \
    AT[p35_ + ss_] = sl_*tpr_ + cl_*tps_;                                   \
    AT[q35_ + rr_] = cl_*tqr_ - sl_*tqs_;                                   \
    AT[q35_ + ss_] = sl_*tqr_ + cl_*tqs_;                                   \
    float2 nvr_, nvs_;                                                      \
    nvr_.x = cl_*vr_.x - sl_*vs_.x;                                         \
    nvr_.y = cl_*vr_.y - sl_*vs_.y;                                         \
    nvs_.x = sl_*vr_.x + cl_*vs_.x;                                         \
    nvs_.y = sl_*vr_.y + cl_*vs_.y;                                         \
    *(float2*)&VT[rr_][i0] = nvr_;                                          \
    *(float2*)&VT[ss_][i0] = nvs_;                                          \
    __syncthreads();                                                        \
} while (0)

__global__ __launch_bounds__(256) void k6_eig(const float* __restrict__ S,
        const float* __restrict__ wq, const float* __restrict__ wk, const float* __restrict__ wv,
        float* __restrict__ QQt, float* __restrict__ KKt, float* __restrict__ Vp) {
    __shared__ float A0[32*35], A1[32*35];   // flat, stride 35
    __shared__ float V0[32][34], V1[32][34]; // 2D, v9 form -> b64 V ops
    __shared__ float sW[3][512];
    __shared__ unsigned int ptabR[31*16];    // (p*35) | (q*35)<<16
    __shared__ unsigned int ptabC[31*16];    // rr | ss<<5 | (rr*35)<<10 | (ss*35)<<21
    __shared__ float Up[32][9];
    __shared__ float Aw[16][9];
    __shared__ float G[8][9];
    __shared__ float Lm[8][9];
    __shared__ float Mm[16][9];
    __shared__ float lam[32];
    int bm = blockIdx.x, b = bm / 3, m = bm % 3;
    int tid = threadIdx.x;
    const float* Sb = S + (size_t)bm*1024;
    for (int i = tid; i < 1024; i += 256) {
        int r_ = i >> 5, c_ = i & 31;
        A0[r_*35 + c_] = Sb[i];
        V0[r_][c_] = (r_ == c_) ? 1.f : 0.f;
    }
    for (int i = tid; i < 512; i += 256) {
        sW[0][i] = wq[i]; sW[1][i] = wk[i]; sW[2][i] = wv[i];
    }
    for (int i = tid; i < 31*16; i += 256) {
        int r_ = i >> 4, k_ = i & 15;
        int p, q; pair_of(r_, k_, p, q);
        ptabR[i] = (unsigned)(p*35) | ((unsigned)(q*35) << 16);
        ptabC[i] = (unsigned)p | ((unsigned)q << 5)
                 | ((unsigned)(p*35) << 10) | ((unsigned)(q*35) << 21);
    }
    __syncthreads();

    int kk_ = tid >> 4, ll_ = tid & 15;     // task: row-pair kk_ x col-pair ll_
    int i0 = kk_ * 2;                       // V column chunk for this task
    // 155 rounds = 77 statically-unrolled pairs (buf0->buf1->buf0) + 1 tail.
    int r = 0;
    for (int gp = 0; gp < 77; ++gp) {
        J_ROUND(r, A0, A1, V0, V1);
        r = (r + 1 == 31) ? 0 : r + 1;
        J_ROUND(r, A1, A0, V1, V0);
        r = (r + 1 == 31) ? 0 : r + 1;
    }
    J_ROUND(r, A0, A1, V0, V1);             // round 155: final state in A1/V1

    // top-8 eigenvalue selection (descending) -> Up (Up[row][rank] = V1[col][row])
    if (tid < 32) lam[tid] = A1[tid*36];    // tid*35 + tid
    __syncthreads();
    if (tid < 32) {
        float lj = lam[tid];
        int rank = 0;
        #pragma unroll
        for (int i = 0; i < 32; ++i) {
            float li = lam[i];
            rank += (li > lj) || (li == lj && i < tid);
        }
        if (rank < PDIM) {
            #pragma unroll
            for (int i = 0; i < 32; ++i) Up[i][rank] = V1[tid][i];
        }
    }
    __syncthreads();

    // projections: P = A (A^T A)^{-1} A^T for A = W * Up  (== qr(A).Q @ Q^T)
    for (int widx = 0; widx < 3; ++widx) {
        if (widx == 2 && m != 2) break;   // V-projection only needed for m==2
        const float* W = sW[widx];
        if (tid < 128) {
            int o = tid >> 3, pp = tid & 7;
            float s = 0.f;
            #pragma unroll
            for (int i = 0; i < 32; ++i) s = fmaf(W[o*32 + i], Up[i][pp], s);
            Aw[o][pp] = s;
        }
        __syncthreads();
        if (tid < 64) {
            int xx = tid >> 3, yy = tid & 7;
            float s = 0.f;
            #pragma unroll
            for (int o = 0; o < 16; ++o) s = fmaf(Aw[o][xx], Aw[o][yy], s);
            G[xx][yy] = s;
        }
        __syncthreads();
        if (tid == 0) {
            float Lr[8][8];
            #pragma unroll
            for (int jj = 0; jj < 8; ++jj) {
                float d = G[jj][jj];
                #pragma unroll
                for (int kk2 = 0; kk2 < 8; ++kk2) if (kk2 < jj) d -= Lr[jj][kk2]*Lr[jj][kk2];
                d = sqrtf(fmaxf(d, 1e-30f));
                float inv = 1.f / d;
                Lr[jj][jj] = d;
                Lm[jj][jj] = inv;     // store INVERSE of diagonal
                #pragma unroll
                for (int ii = 0; ii < 8; ++ii) if (ii > jj) {
                    float v = G[ii][jj];
                    #pragma unroll
                    for (int kk2 = 0; kk2 < 8; ++kk2) if (kk2 < jj) v -= Lr[ii][kk2]*Lr[jj][kk2];
                    v *= inv;
                    Lr[ii][jj] = v;
                    Lm[ii][jj] = v;
                }
            }
        }
        __syncthreads();
        if (tid < 16) {
            int o = tid;
            float a[8], mv[8];
            #pragma unroll
            for (int pp = 0; pp < 8; ++pp) a[pp] = Aw[o][pp];
            #pragma unroll
            for (int jj = 0; jj < 8; ++jj) {
                float v = a[jj];
                #pragma unroll
                for (int kk2 = 0; kk2 < 8; ++kk2) if (kk2 < jj) v -= Lm[jj][kk2]*mv[kk2];
                mv[jj] = v * Lm[jj][jj];
            }
            #pragma unroll
            for (int pp = 0; pp < 8; ++pp) Mm[o][pp] = mv[pp];
        }
        __syncthreads();
        {
            int d = tid >> 4, e = tid & 15;
            float s = 0.f;
            #pragma unroll
            for (int pp = 0; pp < 8; ++pp) s = fmaf(Mm[d][pp], Mm[e][pp], s);
            float* dst = (widx == 0) ? (QQt + (size_t)bm*256)
                       : (widx == 1) ? (KKt + (size_t)bm*256)
                       : (Vp + (size_t)b*256);
            dst[d*16 + e] = s;
        }
        __syncthreads();
    }
}

// ================= K7: attention scores + softmax(i=2) + output linear ==========
__global__ __launch_bounds__(64) void k7_out(const float* __restrict__ QQt,
        const float* __restrict__ KKt, const float* __restrict__ Vp,
        const float* __restrict__ lw, const float* __restrict__ lb,
        float* __restrict__ out) {
    __shared__ float sQ[3][256], sK[3][256], sVp[256], ssc[9], wj[3];
    int b = blockIdx.x, tid = threadIdx.x;
    for (int i = tid; i < 768; i += 64) {
        sQ[i >> 8][i & 255] = QQt[(size_t)b*768 + i];
        sK[i >> 8][i & 255] = KKt[(size_t)b*768 + i];
    }
    for (int i = tid; i < 256; i += 64) sVp[i] = Vp[(size_t)b*256 + i];
    __syncthreads();
    for (int pair = 0; pair < 9; ++pair) {
        int i = pair / 3, j = pair % 3;
        const float* Qj = sQ[j];
        const float* Ki = sK[i];
        float accp = 0.f;
        #pragma unroll
        for (int it = 0; it < 4; ++it) {
            int e = tid + 64*it;
            int d = e >> 4, ee = e & 15;
            float y = 0.f;
            #pragma unroll
            for (int f = 0; f < 16; ++f) {
                float dv = Qj[d*16 + f] - Ki[d*16 + f];
                float ev = Qj[ee*16 + f] - Ki[ee*16 + f];
                y = fmaf(dv, ev, y);
            }
            accp += y*y;
        }
        for (int off = 32; off > 0; off >>= 1) accp += __shfl_down(accp, off, 64);
        if (tid == 0) {
            float E = sqrtf(accp);
            ssc[pair] = 1.f / (1.f + log1pf(E));
        }
        __syncthreads();
    }
    if (tid < 3) {
        int j = tid;
        float e0 = expf(ssc[0*3 + j]), e1 = expf(ssc[1*3 + j]), e2 = expf(ssc[2*3 + j]);
        wj[j] = e2 / (e0 + e1 + e2);
    }
    __syncthreads();
    int o = tid >> 4, g = tid & 15;
    float part = 0.f;
    #pragma unroll
    for (int t = 0; t < 16; ++t) {
        int de = g*16 + t;
        float vv = sVp[de];
        float l0 = lw[o*768 + de];
        float l1 = lw[o*768 + 256 + de];
        float l2 = lw[o*768 + 512 + de];
        part = fmaf(vv, fmaf(wj[0], l0, fmaf(wj[1], l1, wj[2]*l2)), part);
    }
    for (int off = 8; off > 0; off >>= 1) part += __shfl_down(part, off, 16);
    if (g == 0) out[b*4 + o] = part + lb[o];
}

// ================= launch ==========
extern "C" void kernel_launch(void* const* d_in, const int* in_sizes, int n_in,
                              void* d_out, int out_size, void* d_ws, size_t ws_size,
                              hipStream_t stream) {
    const float* x  = (const float*)d_in[0];
    const float* w1 = (const float*)d_in[1];
    // d_in[2] conv1_b: cancels exactly in batch-norm (mean subtraction) -> unused
    const float* g1 = (const float*)d_in[3];
    const float* b1 = (const float*)d_in[4];
    const float* w2 = (const float*)d_in[5];
    // d_in[6] conv2_b: cancels exactly in batch-norm -> unused
    const float* g2 = (const float*)d_in[7];
    const float* b2 = (const float*)d_in[8];
    const float* wq = (const float*)d_in[9];
    const float* wk = (const float*)d_in[10];
    const float* wv = (const float*)d_in[11];
    const float* lw = (const float*)d_in[12];
    const float* lb = (const float*)d_in[13];

    float* ws   = (float*)d_ws;
    float* h1   = ws + OFF_H1;
    float* h2   = ws + OFF_H2;
    float* Sm   = ws + OFF_S;
    unsigned short* WhiG = (unsigned short*)(ws + OFF_WH);
    unsigned short* WloG = (unsigned short*)(ws + OFF_WL);
    float* qqt  = ws + OFF_QQT;
    float* kkt  = ws + OFF_KKT;
    float* vpm  = ws + OFF_VP;
    float* p1a  = ws + OFF_P1;
    float* p2a  = ws + OFF_P2;
    float* bn1p = ws + OFF_BN1;
    float* bn2p = ws + OFF_BN2;

    k0_wsplit<<<(96*288 + 255)/256, 256, 0, stream>>>(w2, WhiG, WloG);
    k1_conv1<<<BSZ, 256, 0, stream>>>(x, w1, h1, p1a);
    k2_bn1<<<CEEG, 64, 0, stream>>>(p1a, g1, b1, bn1p);
    dim3 g3(BSZ, NT8);
    k3_conv2<<<g3, 256, 0, stream>>>(h1, WhiG, WloG, bn1p, h2, p2a);
    k4_bn2<<<C2, 256, 0, stream>>>(p2a, g2, b2, bn2p);
    k5_gram<<<BSZ*3, 256, 0, stream>>>(h2, bn2p, Sm);
    k6_eig<<<BSZ*3, 256, 0, stream>>>(Sm, wq, wk, wv, qqt, kkt, vpm);
    k7_out<<<BSZ, 64, 0, stream>>>(qqt, kkt, vpm, lw, lb, (float*)d_out);
}

// Round 10
// 354.973 us; speedup vs baseline: 1.1056x; 1.0366x over previous
//
#include <hip/hip_runtime.h>
#include <math.h>

#define PDIM 8
#define BSZ 256
#define CEEG 22
#define TLEN 1000
#define KW 12
#define C2 96
#define TOUT 989
#define TSTR 992          // padded h2 row stride (16B-aligned float4 stores)
#define NSWEEP 5          // 4 FAILS (absmax 3.6e-2); 5 = machine floor. LOCKED.
#define NT8 8             // k3 t-tiles of 128
#define NPART (BSZ*NT8*2) // BN2 stat partial groups (2 n-groups per tile)
#define NP1   (BSZ*4)     // BN1 partial groups (k1 split 4x along t)

typedef __attribute__((ext_vector_type(8))) short short8;
typedef __attribute__((ext_vector_type(4))) float floatx4;

// ---- workspace layout (in floats) ----
#define OFF_H1   ((size_t)0)
#define SZ_H1    ((size_t)BSZ*CEEG*TLEN)
#define OFF_H2   (OFF_H1 + SZ_H1)
#define SZ_H2    ((size_t)BSZ*C2*TSTR)
#define OFF_S    (OFF_H2 + SZ_H2)
#define SZ_S     ((size_t)BSZ*3*1024)
// Whi/Wlo (bf16, 96x288 each) ALIAS the S region: written by k0w, consumed by
// k3, then S is (re)written later by k5. No lifetime overlap.
#define OFF_WH   (OFF_S)
#define OFF_WL   (OFF_S + (size_t)13824)
#define OFF_QQT  (OFF_S + SZ_S)
#define SZ_QQT   ((size_t)BSZ*3*256)
#define OFF_KKT  (OFF_QQT + SZ_QQT)
#define OFF_VP   (OFF_KKT + SZ_QQT)
#define SZ_VP    ((size_t)BSZ*256)
#define OFF_P1   (OFF_VP + SZ_VP)
#define SZ_P1    ((size_t)NP1*44)
#define OFF_P2   (OFF_P1 + SZ_P1)
#define SZ_P2    ((size_t)NPART*192)
#define OFF_BN1  (OFF_P2 + SZ_P2)
#define OFF_BN2  (OFF_BN1 + (size_t)64)

__device__ __forceinline__ float elu_f(float z) { return z > 0.f ? z : expm1f(z); }

__device__ __forceinline__ unsigned short f2bf(float x) {
    unsigned u = __float_as_uint(x);
    u += 0x7fffu + ((u >> 16) & 1u);
    return (unsigned short)(u >> 16);
}
__device__ __forceinline__ float bf2f(unsigned short h) {
    return __uint_as_float(((unsigned)h) << 16);
}

// ================= K0w: precompute split-bf16 weights Whi/Wlo [96][288] ==========
__global__ __launch_bounds__(256) void k0_wsplit(const float* __restrict__ w2,
        unsigned short* __restrict__ Whi, unsigned short* __restrict__ Wlo) {
    int i = blockIdx.x*256 + threadIdx.x;
    if (i >= 96*288) return;
    int o = i / 288, kap = i - o*288;
    float v = (kap < 264) ? w2[o*264 + kap] : 0.f;
    unsigned short h = f2bf(v);
    float lo = v - bf2f(h);
    Whi[i] = h;
    Wlo[i] = f2bf(lo);
}

// ======== K1 v2: conv1 + BN1 partials, t-split 4x (4 blocks/CU vs 1) ==========
// Was 256 blocks = 1 block/CU (4 waves) with 4 serial t-iterations/thread and
// exposed HBM latency. Now grid (256,4): each block does one exact 250-t
// quarter (conv1 is pointwise in t - no halo); 4x TLP for latency hiding.
// h1 outputs bit-identical; BN1 partials regrouped into 1024 groups (k2 sums
// them; double-precision final reduce -> ~1e-9 reassociation, harmless).
__global__ __launch_bounds__(256) void k1_conv1(const float* __restrict__ x,
        const float* __restrict__ w1, float* __restrict__ h1,
        float* __restrict__ part1) {
    __shared__ float sw[CEEG*CEEG];       // [o][c]
    __shared__ float red[4][44];
    int b = blockIdx.x;
    int qd = blockIdx.y;                  // t-quarter 0..3
    int tid = threadIdx.x;
    for (int i = tid; i < CEEG*CEEG; i += 256) sw[i] = w1[i];
    __syncthreads();
    float sum[CEEG], sumsq[CEEG];
    #pragma unroll
    for (int o = 0; o < CEEG; ++o) { sum[o] = 0.f; sumsq[o] = 0.f; }
    const float* xb = x + (size_t)b*CEEG*TLEN;
    float* hb = h1 + (size_t)b*CEEG*TLEN;
    int t = qd*250 + tid;                 // 4*250 = 1000 exact
    if (tid < 250) {
        float acc[CEEG];
        #pragma unroll
        for (int o = 0; o < CEEG; ++o) acc[o] = 0.f;
        #pragma unroll 2
        for (int c = 0; c < CEEG; ++c) {
            float xv = xb[c*TLEN + t];
            #pragma unroll
            for (int o = 0; o < CEEG; ++o) acc[o] = fmaf(xv, sw[o*CEEG + c], acc[o]);
        }
        #pragma unroll
        for (int o = 0; o < CEEG; ++o) {
            hb[o*TLEN + t] = acc[o];
            sum[o]  += acc[o];
            sumsq[o] += acc[o]*acc[o];
        }
    }
    int lane = tid & 63, wv = tid >> 6;
    #pragma unroll
    for (int o = 0; o < CEEG; ++o) {
        float s = sum[o], s2 = sumsq[o];
        for (int off = 32; off > 0; off >>= 1) {
            s  += __shfl_down(s,  off, 64);
            s2 += __shfl_down(s2, off, 64);
        }
        if (lane == 0) { red[wv][o] = s; red[wv][CEEG + o] = s2; }
    }
    __syncthreads();
    if (tid < 44) {
        part1[((size_t)b*4 + qd)*44 + tid] =
            red[0][tid] + red[1][tid] + red[2][tid] + red[3][tid];
    }
}

// ================= K2: finalize BN1 params (1 block / channel) ==========
__global__ __launch_bounds__(64) void k2_bn1(const float* __restrict__ part1,
        const float* __restrict__ g, const float* __restrict__ bta, float* __restrict__ p1) {
    int c = blockIdx.x, t = threadIdx.x;
    float s = 0.f, s2 = 0.f;
    for (int blk = t; blk < NP1; blk += 64) {
        s  += part1[(size_t)blk*44 + c];
        s2 += part1[(size_t)blk*44 + CEEG + c];
    }
    for (int off = 32; off > 0; off >>= 1) {
        s  += __shfl_down(s,  off, 64);
        s2 += __shfl_down(s2, off, 64);
    }
    if (t == 0) {
        double N = (double)BSZ * (double)TLEN;
        double mu = (double)s / N, var = (double)s2 / N - mu*mu;
        double scale = (double)g[c] / sqrt(var + 1e-5);
        p1[c] = (float)scale;
        p1[CEEG + c] = (float)((double)bta[c] - mu*scale);
    }
}

// ===== K3 v8: split-bf16 MFMA GEMM, 256 thr, packed-E (hi|lo u32) Xt build ====
// C[96][128] = W[96][288] x X[288][128]. Waves: mg = w&1 (o half), ng = w>>1
// (t half). A-frags: global->register direct, double-buffered. E packed as
// u32 (hi16<<16)|(lo16 trunc) once; Xt build is pure bit-ops.
__global__ __launch_bounds__(256) void k3_conv2(const float* __restrict__ h1,
        const unsigned short* __restrict__ WhiG, const unsigned short* __restrict__ WloG,
        const float* __restrict__ p1, float* __restrict__ h2, float* __restrict__ part2) {
    __shared__ unsigned Epack[22*152];      // (hi16<<16)|(lo16), [c][tt<139]
    __shared__ unsigned short ctab[288];    // kappa -> E offset (c*152+k), 0xFFFF = pad
    __shared__ short XhiL[128*40];          // Xt chunk [t][40], 32 used
    __shared__ short XloL[128*40];
    int b = blockIdx.x;
    int tile = blockIdx.y;                  // 0..7
    int t0 = tile * 128;
    int tid = threadIdx.x;
    int lane = tid & 63, w = tid >> 6;
    int r16 = lane & 15, q = lane >> 4;
    int mg = w & 1, ng = w >> 1;
    const float* hb = h1 + (size_t)b*CEEG*TLEN;

    // stage E window [t0, t0+138] with BN1+ELU, packed hi|lo; zero beyond TLEN
    for (int i = tid; i < 22*139; i += 256) {
        int c = i / 139, tt = i - c*139;
        int t = t0 + tt;
        unsigned pk = 0u;
        if (t < TLEN) {
            float v = elu_f(fmaf(hb[c*TLEN + t], p1[c], p1[CEEG + c]));
            unsigned uv = __float_as_uint(v);
            unsigned hi = uv & 0xFFFF0000u;
            float lo = v - __uint_as_float(hi);
            pk = hi | (__float_as_uint(lo) >> 16);
        }
        Epack[c*152 + tt] = pk;
    }
    for (int i = tid; i < 288; i += 256) {
        int c = i / 12, k = i - c*12;
        ctab[i] = (i < 264) ? (unsigned short)(c*152 + k) : (unsigned short)0xFFFF;
    }

    // A-frag row pointers (this lane's 16B segment per m-tile)
    const unsigned short* ahP[3];
    const unsigned short* alP[3];
    #pragma unroll
    for (int m = 0; m < 3; ++m) {
        int row = mg*48 + m*16 + r16;
        ahP[m] = WhiG + row*288 + q*8;
        alP[m] = WloG + row*288 + q*8;
    }
    short8 ahC[3], alC[3];
    #pragma unroll
    for (int m = 0; m < 3; ++m) {
        ahC[m] = *(const short8*)&ahP[m][0];
        alC[m] = *(const short8*)&alP[m][0];
    }

    floatx4 acc[3][4];
    #pragma unroll
    for (int m = 0; m < 3; ++m)
        #pragma unroll
        for (int nf = 0; nf < 4; ++nf) acc[m][nf] = (floatx4){0.f, 0.f, 0.f, 0.f};

    __syncthreads();                        // Epack ready

    // build Xt for chunk 0 (tasks: u -> row u>>2, 16B chunk u&3)
    #pragma unroll
    for (int s = 0; s < 2; ++s) {
        int u = tid + s*256;
        int t = u >> 2, c4 = u & 3;
        const unsigned short* ct = &ctab[c4*8];
        unsigned dh[4], dl[4];
        #pragma unroll
        for (int jp = 0; jp < 4; ++jp) {
            unsigned short o0 = ct[2*jp], o1 = ct[2*jp+1];
            unsigned p0 = (o0 != 0xFFFFu) ? Epack[o0 + t] : 0u;
            unsigned p1v = (o1 != 0xFFFFu) ? Epack[o1 + t] : 0u;
            dh[jp] = (p0 >> 16) | (p1v & 0xFFFF0000u);
            dl[jp] = (p0 << 16 >> 16) | (p1v << 16);
        }
        *(uint4*)&XhiL[t*40 + c4*8] = make_uint4(dh[0], dh[1], dh[2], dh[3]);
        *(uint4*)&XloL[t*40 + c4*8] = make_uint4(dl[0], dl[1], dl[2], dl[3]);
    }
    __syncthreads();                        // Xt(0) ready

    for (int kc = 0; kc < 9; ++kc) {
        // prefetch A-frags for kc+1 (registers; waits overlap MFMA below)
        short8 ahN[3], alN[3];
        if (kc + 1 < 9) {
            #pragma unroll
            for (int m = 0; m < 3; ++m) {
                ahN[m] = *(const short8*)&ahP[m][(kc+1)*32];
                alN[m] = *(const short8*)&alP[m][(kc+1)*32];
            }
        }
        // MFMA on chunk kc
        #pragma unroll
        for (int nf = 0; nf < 4; ++nf) {
            int tn = (ng*4 + nf)*16 + r16;
            short8 bh = *(const short8*)&XhiL[tn*40 + q*8];
            short8 bl = *(const short8*)&XloL[tn*40 + q*8];
            #pragma unroll
            for (int m = 0; m < 3; ++m) {
                acc[m][nf] = __builtin_amdgcn_mfma_f32_16x16x32_bf16(ahC[m], bh, acc[m][nf], 0, 0, 0);
                acc[m][nf] = __builtin_amdgcn_mfma_f32_16x16x32_bf16(ahC[m], bl, acc[m][nf], 0, 0, 0);
                acc[m][nf] = __builtin_amdgcn_mfma_f32_16x16x32_bf16(alC[m], bh, acc[m][nf], 0, 0, 0);
            }
        }
        if (kc + 1 < 9) {
            __syncthreads();                // Xt(kc) consumed block-wide
            #pragma unroll
            for (int s = 0; s < 2; ++s) {
                int u = tid + s*256;
                int t = u >> 2, c4 = u & 3;
                const unsigned short* ct = &ctab[(kc+1)*32 + c4*8];
                unsigned dh[4], dl[4];
                #pragma unroll
                for (int jp = 0; jp < 4; ++jp) {
                    unsigned short o0 = ct[2*jp], o1 = ct[2*jp+1];
                    unsigned p0 = (o0 != 0xFFFFu) ? Epack[o0 + t] : 0u;
                    unsigned p1v = (o1 != 0xFFFFu) ? Epack[o1 + t] : 0u;
                    dh[jp] = (p0 >> 16) | (p1v & 0xFFFF0000u);
                    dl[jp] = (p0 << 16 >> 16) | (p1v << 16);
                }
                *(uint4*)&XhiL[t*40 + c4*8] = make_uint4(dh[0], dh[1], dh[2], dh[3]);
                *(uint4*)&XloL[t*40 + c4*8] = make_uint4(dl[0], dl[1], dl[2], dl[3]);
            }
            __syncthreads();                // Xt(kc+1) ready
            #pragma unroll
            for (int m = 0; m < 3; ++m) { ahC[m] = ahN[m]; alC[m] = alN[m]; }
        }
    }

    // epilogue: C/D col=lane&15 (t), row=q*4+reg (o). Store + BN2 partials.
    float* h2b = h2 + (size_t)b*C2*TSTR;
    float* pb = part2 + (((size_t)b*NT8 + tile)*2 + ng)*192;
    #pragma unroll
    for (int m = 0; m < 3; ++m) {
        float s[4] = {0.f, 0.f, 0.f, 0.f}, s2[4] = {0.f, 0.f, 0.f, 0.f};
        #pragma unroll
        for (int nf = 0; nf < 4; ++nf) {
            int t = t0 + (ng*4 + nf)*16 + r16;
            bool ok = t < TOUT;
            #pragma unroll
            for (int reg = 0; reg < 4; ++reg) {
                float v = acc[m][nf][reg];
                if (ok) {
                    int o = mg*48 + m*16 + q*4 + reg;
                    h2b[(size_t)o*TSTR + t] = v;
                    s[reg] += v; s2[reg] += v*v;
                }
            }
        }
        #pragma unroll
        for (int reg = 0; reg < 4; ++reg) {
            float a = s[reg], b2 = s2[reg];
            #pragma unroll
            for (int d = 8; d > 0; d >>= 1) {
                a  += __shfl_down(a,  d, 16);
                b2 += __shfl_down(b2, d, 16);
            }
            if (r16 == 0) {
                int o = mg*48 + m*16 + q*4 + reg;
                pb[o] = a; pb[96 + o] = b2;
            }
        }
    }
}

// ================= K4: finalize BN2 params (1 block / channel) ==========
__global__ __launch_bounds__(256) void k4_bn2(const float* __restrict__ part2,
        const float* __restrict__ g, const float* __restrict__ bta, float* __restrict__ p2) {
    __shared__ float rs[4], rs2[4];
    int q = blockIdx.x, t = threadIdx.x;
    float s = 0.f, s2 = 0.f;
    for (int blk = t; blk < NPART; blk += 256) {
        s  += part2[(size_t)blk*192 + q];
        s2 += part2[(size_t)blk*192 + 96 + q];
    }
    for (int off = 32; off > 0; off >>= 1) {
        s  += __shfl_down(s,  off, 64);
        s2 += __shfl_down(s2, off, 64);
    }
    int lane = t & 63, wv = t >> 6;
    if (lane == 0) { rs[wv] = s; rs2[wv] = s2; }
    __syncthreads();
    if (t == 0) {
        double S  = (double)rs[0]  + rs[1]  + rs[2]  + rs[3];
        double S2 = (double)rs2[0] + rs2[1] + rs2[2] + rs2[3];
        double N = (double)BSZ * (double)TOUT;
        double mu = S / N, var = S2 / N - mu*mu;
        double scale = (double)g[q] / sqrt(var + 1e-5);
        p2[q] = (float)scale;
        p2[C2 + q] = (float)((double)bta[q] - mu*scale);
    }
}

// ===== K5 v2: Gram, 4x4 tiles, wave-private staging, no inner barriers ==========
__global__ __launch_bounds__(256) void k5_gram(const float* __restrict__ h2,
        const float* __restrict__ p2, float* __restrict__ S) {
    __shared__ float smem[4*2176];          // per-wave [32][68]; overlaid red [64][17]
    int bm = blockIdx.x;
    int b = bm / 3, m = bm % 3;
    int tid = threadIdx.x;
    int w = tid >> 6, lane = tid & 63;
    float* sx = smem + w*2176;
    const float* hb = h2 + ((size_t)b*C2 + m*32)*TSTR;
    int srow = lane >> 1;
    int scol = (lane & 1) * 32;
    float sc = p2[m*32 + srow], sh = p2[C2 + m*32 + srow];
    int r0 = (lane >> 3) << 2, c0 = (lane & 7) << 2;
    float acc[4][4];
    #pragma unroll
    for (int i = 0; i < 4; ++i)
        #pragma unroll
        for (int j = 0; j < 4; ++j) acc[i][j] = 0.f;

    for (int t0 = w*64; t0 < TOUT; t0 += 256) {
        const float* src = &hb[(size_t)srow*TSTR + t0 + scol];
        float* drow = &sx[srow*68 + scol];
        if (t0 + 63 < TOUT) {
            #pragma unroll
            for (int j = 0; j < 8; ++j) {
                float4 xv = *(const float4*)&src[4*j];
                float4 v;
                v.x = elu_f(fmaf(xv.x, sc, sh));
                v.y = elu_f(fmaf(xv.y, sc, sh));
                v.z = elu_f(fmaf(xv.z, sc, sh));
                v.w = elu_f(fmaf(xv.w, sc, sh));
                *(float4*)&drow[4*j] = v;
            }
        } else {
            #pragma unroll
            for (int j = 0; j < 8; ++j) {
                float4 xv = *(const float4*)&src[4*j];
                int tb = t0 + scol + 4*j;
                float4 v;
                v.x = (tb + 0 < TOUT) ? elu_f(fmaf(xv.x, sc, sh)) : 0.f;
                v.y = (tb + 1 < TOUT) ? elu_f(fmaf(xv.y, sc, sh)) : 0.f;
                v.z = (tb + 2 < TOUT) ? elu_f(fmaf(xv.z, sc, sh)) : 0.f;
                v.w = (tb + 3 < TOUT) ? elu_f(fmaf(xv.w, sc, sh)) : 0.f;
                *(float4*)&drow[4*j] = v;
            }
        }
        #pragma unroll
        for (int tc = 0; tc < 16; ++tc) {
            float4 a0 = *(const float4*)&sx[(r0+0)*68 + tc*4];
            float4 a1 = *(const float4*)&sx[(r0+1)*68 + tc*4];
            float4 a2 = *(const float4*)&sx[(r0+2)*68 + tc*4];
            float4 a3 = *(const float4*)&sx[(r0+3)*68 + tc*4];
            float4 b0 = *(const float4*)&sx[(c0+0)*68 + tc*4];
            float4 b1 = *(const float4*)&sx[(c0+1)*68 + tc*4];
            float4 b2 = *(const float4*)&sx[(c0+2)*68 + tc*4];
            float4 b3 = *(const float4*)&sx[(c0+3)*68 + tc*4];
            #pragma unroll
            for (int i = 0; i < 4; ++i) {
                float4 ai = (i == 0) ? a0 : (i == 1) ? a1 : (i == 2) ? a2 : a3;
                acc[i][0] = fmaf(ai.x, b0.x, fmaf(ai.y, b0.y, fmaf(ai.z, b0.z, fmaf(ai.w, b0.w, acc[i][0]))));
                acc[i][1] = fmaf(ai.x, b1.x, fmaf(ai.y, b1.y, fmaf(ai.z, b1.z, fmaf(ai.w, b1.w, acc[i][1]))));
                acc[i][2] = fmaf(ai.x, b2.x, fmaf(ai.y, b2.y, fmaf(ai.z, b2.z, fmaf(ai.w, b2.w, acc[i][2]))));
                acc[i][3] = fmaf(ai.x, b3.x, fmaf(ai.y, b3.y, fmaf(ai.z, b3.z, fmaf(ai.w, b3.w, acc[i][3]))));
            }
        }
    }

    float* red = smem + w*2176;
    #pragma unroll
    for (int i = 0; i < 4; ++i)
        #pragma unroll
        for (int j = 0; j < 4; ++j)
            red[lane*17 + i*4 + j] = acc[i][j];
    __syncthreads();
    int e0 = tid * 4;
    int r = e0 >> 5, c = e0 & 31;
    int tl = (r >> 2)*8 + (c >> 2);
    int sb = (r & 3)*4;
    float o0 = 0.f, o1 = 0.f, o2 = 0.f, o3 = 0.f;
    #pragma unroll
    for (int ww = 0; ww < 4; ++ww) {
        const float* rp = smem + ww*2176 + tl*17 + sb;
        o0 += rp[0]; o1 += rp[1]; o2 += rp[2]; o3 += rp[3];
    }
    float* Sb2 = S + (size_t)bm*1024;
    *(float4*)&Sb2[e0] = make_float4(o0, o1, o2, o3);
}

// ===== K6 v12 (FROZEN): v9 LDS stream (2D V, b64) + packed tables for A ======
// 110.4us, conflicts 1.72e7, VALU ~49%. Further k6 gains need a register-
// resident redesign (high risk, ~-20us ceiling) -> frozen; pivot to pipeline.
__device__ __forceinline__ void pair_of(int r, int k, int& p, int& q) {
    if (k == 0) { p = r; q = 31; }
    else {
        int a = (r + k) % 31;
        int b2 = (r - k + 31) % 31;
        p = min(a, b2); q = max(a, b2);
    }
}

__device__ __forceinline__ void jacobi_cs(float app, float aqq, float apq,
                                          float& c, float& s) {
    c = 1.f; s = 0.f;
    if (apq != 0.f) {
        float tau = (aqq - app) * 0.5f * __builtin_amdgcn_rcpf(apq);
        float sq  = __builtin_amdgcn_sqrtf(fmaf(tau, tau, 1.f));
        float tt  = (tau >= 0.f ? 1.f : -1.f) * __builtin_amdgcn_rcpf(fabsf(tau) + sq);
        c = __builtin_amdgcn_rsqf(fmaf(tt, tt, 1.f));
        s = tt * c;
        if (!(c == c) || !(s == s)) { c = 1.f; s = 0.f; }
    }
}

// one Jacobi round: read AF/VF (state), write AT/VT (next), 1 barrier.
// A* flat stride 35 (table offsets); V* 2D [32][34] (b64-provable, v9 form).
#define J_ROUND(RR_, AF, AT, VF, VT) do {                                   \
    int base_ = (RR_) << 4;                                                 \
    unsigned tr_ = ptabR[base_ + kk_];                                      \
    unsigned tc_ = ptabC[base_ + ll_];                                      \
    int p35_ = tr_ & 0xffff, q35_ = (int)(tr_ >> 16);                       \
    int rr_ = tc_ & 31, ss_ = (tc_ >> 5) & 31;                              \
    int rr35_ = (tc_ >> 10) & 2047, ss35_ = (int)(tc_ >> 21);               \
    float brr_ = AF[rr35_ + rr_], bss_ = AF[ss35_ + ss_], brs_ = AF[rr35_ + ss_]; \
    float apr_ = AF[p35_ + rr_], aps_ = AF[p35_ + ss_];                     \
    float aqr_ = AF[q35_ + rr_], aqs_ = AF[q35_ + ss_];                     \
    float2 vr_ = *(const float2*)&VF[rr_][i0];                              \
    float2 vs_ = *(const float2*)&VF[ss_][i0];                              \
    float cl_, sl_;                                                         \
    jacobi_cs(brr_, bss_, brs_, cl_, sl_);                                  \
    float ck_ = __shfl(cl_, kk_, 64);                                       \
    float sk_ = __shfl(sl_, kk_, 64);                                       \
    float tpr_ = ck_*apr_ - sk_*aqr_;                                       \
    float tqr_ = sk_*apr_ + ck_*aqr_;                                       \
    float tps_ = ck_*aps_ - sk_*aqs_;                                       \
    float tqs_ = sk_*aps_ + ck_*aqs_;                                       \
    AT[p35_ + rr_] = cl_*tpr_ - sl_*tps_;                                   \
    AT[p35_ + ss_] = sl_*tpr_ + cl_*tps_;                                   \
    AT[q35_ + rr_] = cl_*tqr_ - sl_*tqs_;                                   \
    AT[q35_ + ss_] = sl_*tqr_ + cl_*tqs_;                                   \
    float2 nvr_, nvs_;                                                      \
    nvr_.x = cl_*vr_.x - sl_*vs_.x;                                         \
    nvr_.y = cl_*vr_.y - sl_*vs_.y;                                         \
    nvs_.x = sl_*vr_.x + cl_*vs_.x;                                         \
    nvs_.y = sl_*vr_.y + cl_*vs_.y;                                         \
    *(float2*)&VT[rr_][i0] = nvr_;                                          \
    *(float2*)&VT[ss_][i0] = nvs_;                                          \
    __syncthreads();                                                        \
} while (0)

__global__ __launch_bounds__(256) void k6_eig(const float* __restrict__ S,
        const float* __restrict__ wq, const float* __restrict__ wk, const float* __restrict__ wv,
        float* __restrict__ QQt, float* __restrict__ KKt, float* __restrict__ Vp) {
    __shared__ float A0[32*35], A1[32*35];   // flat, stride 35
    __shared__ float V0[32][34], V1[32][34]; // 2D, v9 form -> b64 V ops
    __shared__ float sW[3][512];
    __shared__ unsigned int ptabR[31*16];    // (p*35) | (q*35)<<16
    __shared__ unsigned int ptabC[31*16];    // rr | ss<<5 | (rr*35)<<10 | (ss*35)<<21
    __shared__ float Up[32][9];
    __shared__ float Aw[16][9];
    __shared__ float G[8][9];
    __shared__ float Lm[8][9];
    __shared__ float Mm[16][9];
    __shared__ float lam[32];
    int bm = blockIdx.x, b = bm / 3, m = bm % 3;
    int tid = threadIdx.x;
    const float* Sb = S + (size_t)bm*1024;
    for (int i = tid; i < 1024; i += 256) {
        int r_ = i >> 5, c_ = i & 31;
        A0[r_*35 + c_] = Sb[i];
        V0[r_][c_] = (r_ == c_) ? 1.f : 0.f;
    }
    for (int i = tid; i < 512; i += 256) {
        sW[0][i] = wq[i]; sW[1][i] = wk[i]; sW[2][i] = wv[i];
    }
    for (int i = tid; i < 31*16; i += 256) {
        int r_ = i >> 4, k_ = i & 15;
        int p, q; pair_of(r_, k_, p, q);
        ptabR[i] = (unsigned)(p*35) | ((unsigned)(q*35) << 16);
        ptabC[i] = (unsigned)p | ((unsigned)q << 5)
                 | ((unsigned)(p*35) << 10) | ((unsigned)(q*35) << 21);
    }
    __syncthreads();

    int kk_ = tid >> 4, ll_ = tid & 15;     // task: row-pair kk_ x col-pair ll_
    int i0 = kk_ * 2;                       // V column chunk for this task
    // 155 rounds = 77 statically-unrolled pairs (buf0->buf1->buf0) + 1 tail.
    int r = 0;
    for (int gp = 0; gp < 77; ++gp) {
        J_ROUND(r, A0, A1, V0, V1);
        r = (r + 1 == 31) ? 0 : r + 1;
        J_ROUND(r, A1, A0, V1, V0);
        r = (r + 1 == 31) ? 0 : r + 1;
    }
    J_ROUND(r, A0, A1, V0, V1);             // round 155: final state in A1/V1

    // top-8 eigenvalue selection (descending) -> Up (Up[row][rank] = V1[col][row])
    if (tid < 32) lam[tid] = A1[tid*36];    // tid*35 + tid
    __syncthreads();
    if (tid < 32) {
        float lj = lam[tid];
        int rank = 0;
        #pragma unroll
        for (int i = 0; i < 32; ++i) {
            float li = lam[i];
            rank += (li > lj) || (li == lj && i < tid);
        }
        if (rank < PDIM) {
            #pragma unroll
            for (int i = 0; i < 32; ++i) Up[i][rank] = V1[tid][i];
        }
    }
    __syncthreads();

    // projections: P = A (A^T A)^{-1} A^T for A = W * Up  (== qr(A).Q @ Q^T)
    for (int widx = 0; widx < 3; ++widx) {
        if (widx == 2 && m != 2) break;   // V-projection only needed for m==2
        const float* W = sW[widx];
        if (tid < 128) {
            int o = tid >> 3, pp = tid & 7;
            float s = 0.f;
            #pragma unroll
            for (int i = 0; i < 32; ++i) s = fmaf(W[o*32 + i], Up[i][pp], s);
            Aw[o][pp] = s;
        }
        __syncthreads();
        if (tid < 64) {
            int xx = tid >> 3, yy = tid & 7;
            float s = 0.f;
            #pragma unroll
            for (int o = 0; o < 16; ++o) s = fmaf(Aw[o][xx], Aw[o][yy], s);
            G[xx][yy] = s;
        }
        __syncthreads();
        if (tid == 0) {
            float Lr[8][8];
            #pragma unroll
            for (int jj = 0; jj < 8; ++jj) {
                float d = G[jj][jj];
                #pragma unroll
                for (int kk2 = 0; kk2 < 8; ++kk2) if (kk2 < jj) d -= Lr[jj][kk2]*Lr[jj][kk2];
                d = sqrtf(fmaxf(d, 1e-30f));
                float inv = 1.f / d;
                Lr[jj][jj] = d;
                Lm[jj][jj] = inv;     // store INVERSE of diagonal
                #pragma unroll
                for (int ii = 0; ii < 8; ++ii) if (ii > jj) {
                    float v = G[ii][jj];
                    #pragma unroll
                    for (int kk2 = 0; kk2 < 8; ++kk2) if (kk2 < jj) v -= Lr[ii][kk2]*Lr[jj][kk2];
                    v *= inv;
                    Lr[ii][jj] = v;
                    Lm[ii][jj] = v;
                }
            }
        }
        __syncthreads();
        if (tid < 16) {
            int o = tid;
            float a[8], mv[8];
            #pragma unroll
            for (int pp = 0; pp < 8; ++pp) a[pp] = Aw[o][pp];
            #pragma unroll
            for (int jj = 0; jj < 8; ++jj) {
                float v = a[jj];
                #pragma unroll
                for (int kk2 = 0; kk2 < 8; ++kk2) if (kk2 < jj) v -= Lm[jj][kk2]*mv[kk2];
                mv[jj] = v * Lm[jj][jj];
            }
            #pragma unroll
            for (int pp = 0; pp < 8; ++pp) Mm[o][pp] = mv[pp];
        }
        __syncthreads();
        {
            int d = tid >> 4, e = tid & 15;
            float s = 0.f;
            #pragma unroll
            for (int pp = 0; pp < 8; ++pp) s = fmaf(Mm[d][pp], Mm[e][pp], s);
            float* dst = (widx == 0) ? (QQt + (size_t)bm*256)
                       : (widx == 1) ? (KKt + (size_t)bm*256)
                       : (Vp + (size_t)b*256);
            dst[d*16 + e] = s;
        }
        __syncthreads();
    }
}

// ===== K7 v2: 256 thr, all 9 score-pairs in parallel (was 9 serial rounds) ====
// Was 64 thr (1 wave/CU) with 9 serially-barriered pair rounds. Now: pair g
// handled by 16-lane group (lanes 16g..16g+15, g<9, first 3 waves); lane = d
// row, sums 16 ee terms (Qj/Ki group reads are same-address broadcasts).
// shfl-16 reduce, 1 barrier. accp reassociation ~1e-7 rel (norm) - invisible
// at the 2^-11 output floor.
__global__ __launch_bounds__(256) void k7_out(const float* __restrict__ QQt,
        const float* __restrict__ KKt, const float* __restrict__ Vp,
        const float* __restrict__ lw, const float* __restrict__ lb,
        float* __restrict__ out) {
    __shared__ float sQ[3][256], sK[3][256], sVp[256], ssc[9], wj[3];
    int b = blockIdx.x, tid = threadIdx.x;
    for (int i = tid; i < 768; i += 256) {
        sQ[i >> 8][i & 255] = QQt[(size_t)b*768 + i];
        sK[i >> 8][i & 255] = KKt[(size_t)b*768 + i];
    }
    if (tid < 256) sVp[tid] = Vp[(size_t)b*256 + tid];
    __syncthreads();
    if (tid < 144) {
        int g = tid >> 4, l = tid & 15;     // pair g, d-row l
        int i = g / 3, j = g % 3;
        const float* Qj = sQ[j];
        const float* Ki = sK[i];
        float dv[16];
        #pragma unroll
        for (int f = 0; f < 16; ++f) dv[f] = Qj[l*16 + f] - Ki[l*16 + f];
        float accp = 0.f;
        #pragma unroll
        for (int ee = 0; ee < 16; ++ee) {
            float y = 0.f;
            #pragma unroll
            for (int f = 0; f < 16; ++f) {
                float ev = Qj[ee*16 + f] - Ki[ee*16 + f];   // broadcast
                y = fmaf(dv[f], ev, y);
            }
            accp += y*y;
        }
        #pragma unroll
        for (int off = 8; off > 0; off >>= 1) accp += __shfl_down(accp, off, 16);
        if (l == 0) {
            float E = sqrtf(accp);
            ssc[g] = 1.f / (1.f + log1pf(E));
        }
    }
    __syncthreads();
    if (tid < 3) {
        int j = tid;
        float e0 = expf(ssc[0*3 + j]), e1 = expf(ssc[1*3 + j]), e2 = expf(ssc[2*3 + j]);
        wj[j] = e2 / (e0 + e1 + e2);
    }
    __syncthreads();
    if (tid < 64) {
        int o = tid >> 4, g = tid & 15;
        float part = 0.f;
        #pragma unroll
        for (int t = 0; t < 16; ++t) {
            int de = g*16 + t;
            float vv = sVp[de];
            float l0 = lw[o*768 + de];
            float l1 = lw[o*768 + 256 + de];
            float l2 = lw[o*768 + 512 + de];
            part = fmaf(vv, fmaf(wj[0], l0, fmaf(wj[1], l1, wj[2]*l2)), part);
        }
        #pragma unroll
        for (int off = 8; off > 0; off >>= 1) part += __shfl_down(part, off, 16);
        if (g == 0) out[b*4 + o] = part + lb[o];
    }
}

// ================= launch ==========
extern "C" void kernel_launch(void* const* d_in, const int* in_sizes, int n_in,
                              void* d_out, int out_size, void* d_ws, size_t ws_size,
                              hipStream_t stream) {
    const float* x  = (const float*)d_in[0];
    const float* w1 = (const float*)d_in[1];
    // d_in[2] conv1_b: cancels exactly in batch-norm (mean subtraction) -> unused
    const float* g1 = (const float*)d_in[3];
    const float* b1 = (const float*)d_in[4];
    const float* w2 = (const float*)d_in[5];
    // d_in[6] conv2_b: cancels exactly in batch-norm -> unused
    const float* g2 = (const float*)d_in[7];
    const float* b2 = (const float*)d_in[8];
    const float* wq = (const float*)d_in[9];
    const float* wk = (const float*)d_in[10];
    const float* wv = (const float*)d_in[11];
    const float* lw = (const float*)d_in[12];
    const float* lb = (const float*)d_in[13];

    float* ws   = (float*)d_ws;
    float* h1   = ws + OFF_H1;
    float* h2   = ws + OFF_H2;
    float* Sm   = ws + OFF_S;
    unsigned short* WhiG = (unsigned short*)(ws + OFF_WH);
    unsigned short* WloG = (unsigned short*)(ws + OFF_WL);
    float* qqt  = ws + OFF_QQT;
    float* kkt  = ws + OFF_KKT;
    float* vpm  = ws + OFF_VP;
    float* p1a  = ws + OFF_P1;
    float* p2a  = ws + OFF_P2;
    float* bn1p = ws + OFF_BN1;
    float* bn2p = ws + OFF_BN2;

    k0_wsplit<<<(96*288 + 255)/256, 256, 0, stream>>>(w2, WhiG, WloG);
    dim3 g1d(BSZ, 4);
    k1_conv1<<<g1d, 256, 0, stream>>>(x, w1, h1, p1a);
    k2_bn1<<<CEEG, 64, 0, stream>>>(p1a, g1, b1, bn1p);
    dim3 g3(BSZ, NT8);
    k3_conv2<<<g3, 256, 0, stream>>>(h1, WhiG, WloG, bn1p, h2, p2a);
    k4_bn2<<<C2, 256, 0, stream>>>(p2a, g2, b2, bn2p);
    k5_gram<<<BSZ*3, 256, 0, stream>>>(h2, bn2p, Sm);
    k6_eig<<<BSZ*3, 256, 0, stream>>>(Sm, wq, wk, wv, qqt, kkt, vpm);
    k7_out<<<BSZ, 256, 0, stream>>>(qqt, kkt, vpm, lw, lb, (float*)d_out);
}